// Round 4
// baseline (139.467 us; speedup 1.0000x reference)
//
#include <hip/hip_runtime.h>

typedef __attribute__((ext_vector_type(8))) short short8v;
typedef __attribute__((ext_vector_type(4))) float f32x4;
typedef __attribute__((ext_vector_type(16))) float f32x16;
typedef unsigned short u16;
typedef unsigned int u32;

#define MFMA __builtin_amdgcn_mfma_f32_16x16x32_bf16
#define MFMA32 __builtin_amdgcn_mfma_f32_32x32x16_bf16

// ---------- helpers ----------
__device__ __forceinline__ u16 f2b(float f) {
  u32 u = __float_as_uint(f);
  u = (u + 0x7FFFu + ((u >> 16) & 1u)) >> 16;
  return (u16)u;
}
__device__ __forceinline__ float b2f(u16 b) {
  return __uint_as_float(((u32)b) << 16);
}
__device__ __forceinline__ void g2l16(const void* g, void* l) {
  __builtin_amdgcn_global_load_lds(
      (const __attribute__((address_space(1))) unsigned int*)g,
      (__attribute__((address_space(3))) unsigned int*)l, 16, 0, 0);
}

// sizes
#define N_TOK 2048
#define DIM 1024
#define NH 16
#define HD 64

// Q pre-scale: hd^-0.5 * log2(e)  (softmax runs in exp2 domain)
#define QSCALE 0.18033688011112042f

// workspace layout (bytes)
#define OFF_PERM 0
#define OFF_CNT 8192
#define OFF_XPB 16384
#define OFF_WT (OFF_XPB + 4194304)          // 16 MB: [tensor][expert][1024][1024] bf16, WT[n][k]
#define OFF_Q (OFF_WT + 16777216)
#define OFF_K (OFF_Q + 4194304)
#define OFF_V (OFF_K + 4194304)
#define OFF_VT (OFF_V + 4194304)            // [16][64][2048] bf16
#define OFF_AT (OFF_VT + 4194304)
#define OFF_O (OFF_AT + 4194304)            // f32 [2048][1024]

// ---------- prep: modality ids, stable partition perm, cnt0 ----------
__global__ __launch_bounds__(256) void prep_kernel(const void* __restrict__ masks,
                                                   int* __restrict__ perm,
                                                   int* __restrict__ cnt) {
  const int tid = threadIdx.x;
  __shared__ u32 red[256];
  __shared__ int scan[256];
  const u32* mw = (const u32*)masks;
  u32 mx = 0;
  for (int i = tid; i < 1024; i += 256) { u32 v = mw[i]; mx = mx > v ? mx : v; }
  red[tid] = mx;
  __syncthreads();
  for (int off = 128; off; off >>= 1) {
    if (tid < off) red[tid] = red[tid] > red[tid + off] ? red[tid] : red[tid + off];
    __syncthreads();
  }
  const bool isbyte = red[0] > 1u;
  int md[8];
  int c0loc = 0;
  #pragma unroll
  for (int j = 0; j < 8; ++j) {
    const int n = tid * 8 + j;
    int m1;
    if (isbyte) m1 = ((const unsigned char*)masks)[N_TOK + n] != 0;
    else        m1 = mw[N_TOK + n] != 0;
    md[j] = m1;
    c0loc += (m1 == 0);
  }
  scan[tid] = c0loc;
  __syncthreads();
  for (int off = 1; off < 256; off <<= 1) {
    int v = (tid >= off) ? scan[tid - off] : 0;
    __syncthreads();
    scan[tid] += v;
    __syncthreads();
  }
  const int incl = scan[tid];
  const int total0 = scan[255];
  const int excl0 = incl - c0loc;
  int p0 = excl0;
  int p1 = total0 + (tid * 8 - excl0);
  #pragma unroll
  for (int j = 0; j < 8; ++j) {
    const int n = tid * 8 + j;
    if (!md[j]) perm[p0++] = n; else perm[p1++] = n;
  }
  if (tid == 0) cnt[0] = total0;
}

// ---------- gather + cast x -> xp bf16 ----------
__global__ __launch_bounds__(256) void gather_cast(const float* __restrict__ x,
                                                   const int* __restrict__ perm,
                                                   u16* __restrict__ xpb) {
  const int i = blockIdx.x;
  const int src = perm[i];
  const int tid = threadIdx.x;
  float4 v = ((const float4*)(x + (size_t)src * DIM))[tid];
  ushort4 o;
  o.x = f2b(v.x); o.y = f2b(v.y); o.z = f2b(v.z); o.w = f2b(v.w);
  ((ushort4*)(xpb + (size_t)i * DIM))[tid] = o;
}

// ---------- weight transpose-cast: W[k][n] f32 -> WT[n][k] bf16 ----------
__global__ __launch_bounds__(256) void wcast(const float* __restrict__ wq,
                                             const float* __restrict__ wk,
                                             const float* __restrict__ wv,
                                             const float* __restrict__ wo,
                                             u16* __restrict__ wT) {
  const int mat = blockIdx.z;               // tensor*2 + expert
  const int tensor = mat >> 1, expert = mat & 1;
  const float* src = (tensor == 0) ? wq : (tensor == 1) ? wk : (tensor == 2) ? wv : wo;
  src += (size_t)expert * (1 << 20);
  u16* dst = wT + ((size_t)mat << 20);
  const int k0 = blockIdx.x * 32, n0 = blockIdx.y * 32;
  const int tx = threadIdx.x, ty = threadIdx.y;
  __shared__ float t[32][33];
  #pragma unroll
  for (int r = 0; r < 4; ++r)
    t[ty + 8 * r][tx] = src[(size_t)(k0 + ty + 8 * r) * DIM + n0 + tx];
  __syncthreads();
  #pragma unroll
  for (int r = 0; r < 4; ++r)
    dst[(size_t)(n0 + ty + 8 * r) * DIM + k0 + tx] = f2b(t[tx][ty + 8 * r]);
}

// ---------- V transpose per head: v[n][h*64+d] -> vT[h][d][n] ----------
__global__ __launch_bounds__(256) void vtrans(const u16* __restrict__ v,
                                              u16* __restrict__ vT) {
  const int h = blockIdx.z;
  const int n0 = blockIdx.x * 32, d0 = blockIdx.y * 32;
  const int tx = threadIdx.x, ty = threadIdx.y;
  __shared__ u16 t[32][33];
  #pragma unroll
  for (int r = 0; r < 4; ++r)
    t[ty + 8 * r][tx] = v[(size_t)(n0 + ty + 8 * r) * DIM + h * HD + d0 + tx];
  __syncthreads();
  #pragma unroll
  for (int r = 0; r < 4; ++r)
    vT[(size_t)(h * HD + d0 + ty + 8 * r) * N_TOK + n0 + tx] = t[tx][ty + 8 * r];
}

// ---------- expert GEMM ----------
template <int OUTF32>
__global__ __launch_bounds__(256) void gemm_exp(const u16* __restrict__ X,
                                                const u16* __restrict__ WTall,
                                                int tensor0, float scale0,
                                                void* __restrict__ o0,
                                                void* __restrict__ o1,
                                                void* __restrict__ o2,
                                                const int* __restrict__ cntp) {
  const int z = blockIdx.z;
  const int e = blockIdx.y >> 4;
  const int mt = blockIdx.y & 15;
  const int c0 = cntp[0];
  const int lo = e ? c0 : 0;
  const int hi = e ? N_TOK : c0;
  const int rb = mt * 128;
  if (rb >= hi || rb + 128 <= lo) return;
  const int cb = blockIdx.x * 128;
  void* OUT = (z == 0) ? o0 : (z == 1) ? o1 : o2;
  const u16* W = WTall + ((size_t)((tensor0 + z) * 2 + e) << 20);
  const float scl = (z == 0) ? scale0 : 1.f;

  const int tid = threadIdx.x;
  const int w = tid >> 6, l = tid & 63, lg = l >> 4, ln = l & 15;
  const int wm = (w >> 1) * 64, wn = (w & 1) * 64;

  __shared__ __align__(16) char smem[32768];

  auto stage = [&](int it, int b_) {
    const int k0b = it * 64;
    #pragma unroll
    for (int c = 0; c < 2; ++c) {
      const int lb = (tid + c * 256) * 16;
      const int row = lb >> 6, colb = lb & 63;
      g2l16((const char*)X + (size_t)(rb + row) * 2048 + k0b + colb,
            &smem[b_ * 16384 + lb]);
      g2l16((const char*)W + (size_t)(cb + row) * 2048 + k0b + colb,
            &smem[b_ * 16384 + 8192 + lb]);
    }
  };

  f32x4 acc[4][4];
  #pragma unroll
  for (int i = 0; i < 4; ++i)
    #pragma unroll
    for (int j = 0; j < 4; ++j) acc[i][j] = (f32x4){0.f, 0.f, 0.f, 0.f};

  stage(0, 0);
  __syncthreads();
  for (int it = 0; it < 32; ++it) {
    const int b_ = it & 1;
    if (it < 31) stage(it + 1, b_ ^ 1);
    short8v a[4], bb[4];
    #pragma unroll
    for (int mi = 0; mi < 4; ++mi)
      a[mi] = *(const short8v*)&smem[b_ * 16384 + (wm + mi * 16 + ln) * 64 + lg * 16];
    #pragma unroll
    for (int ni = 0; ni < 4; ++ni)
      bb[ni] = *(const short8v*)&smem[b_ * 16384 + 8192 + (wn + ni * 16 + ln) * 64 + lg * 16];
    __builtin_amdgcn_s_setprio(1);
    #pragma unroll
    for (int mi = 0; mi < 4; ++mi)
      #pragma unroll
      for (int ni = 0; ni < 4; ++ni)
        acc[mi][ni] = MFMA(a[mi], bb[ni], acc[mi][ni], 0, 0, 0);
    __builtin_amdgcn_s_setprio(0);
    __syncthreads();
  }

  #pragma unroll
  for (int mi = 0; mi < 4; ++mi) {
    #pragma unroll
    for (int r = 0; r < 4; ++r) {
      const int row = rb + wm + mi * 16 + lg * 4 + r;
      if (row >= lo && row < hi) {
        #pragma unroll
        for (int ni = 0; ni < 4; ++ni) {
          const int col = cb + wn + ni * 16 + ln;
          const float vv = acc[mi][ni][r] * scl;
          if (OUTF32) ((float*)OUT)[(size_t)row * DIM + col] = vv;
          else ((u16*)OUT)[(size_t)row * DIM + col] = f2b(vv);
        }
      }
    }
  }
}

// ---------- flash attention: 32x32x16 MFMA, all operands global->register ----------
// grid (32 qtiles, 16 heads); block = 4 waves: wave w -> qgrp g=w&1 (32 q rows),
// key-half kh=w>>1 (1024 keys, 16 iters of 64). No LDS/barriers in main loop;
// K ping-pong prefetch in registers, V issued at iter top (hidden under QK+softmax).
__global__ __launch_bounds__(256, 2) void attn_fwd(const u16* __restrict__ qg,
                                                   const u16* __restrict__ kg,
                                                   const u16* __restrict__ vTg,
                                                   u16* __restrict__ og) {
  const int qt = blockIdx.x, h = blockIdx.y;
  const int tid = threadIdx.x, w = tid >> 6, l = tid & 63;
  const int g = w & 1, kh = w >> 1;
  const int q31 = l & 31;                    // lane's q (in S^T) / d (in O)
  const int hi = l >> 5;                     // lane half
  const int hi16 = hi * 16, hi4 = hi * 4;

  __shared__ __align__(16) char smem[17408]; // merge: Obuf 16KB + m/l 1KB

  // Q fragments (B-operand): lane q-col = q31
  const char* qrow = (const char*)qg + ((size_t)(qt * 64 + g * 32 + q31)) * 2048 + h * 128;
  short8v qf[4];
  #pragma unroll
  for (int t = 0; t < 4; ++t) qf[t] = *(const short8v*)(qrow + t * 32 + hi16);

  // per-lane global bases.  K A-frag (it,ks,t): pK + it*131072 + ks*65536 + t*32
  // V^T B-frag (it,ks,kk,r2): pV{r2} + it*128 + ks*64 + kk*32
  const char* pK = (const char*)kg + ((size_t)(kh * 1024 + q31)) * 2048 + h * 128 + hi16;
  const char* pV0 = (const char*)vTg + ((size_t)(h * 64 + q31)) * 4096 + kh * 2048 + hi16;
  const char* pV1 = pV0 + 32 * 4096;

  float m_s = -1e30f, l_s = 0.f;
  f32x16 accO[2];
  #pragma unroll
  for (int dt = 0; dt < 2; ++dt)
    #pragma unroll
    for (int r = 0; r < 16; ++r) accO[dt][r] = 0.f;

  short8v kA[8], kB[8];
  #pragma unroll
  for (int ks = 0; ks < 2; ++ks)
    #pragma unroll
    for (int t = 0; t < 4; ++t)
      kA[ks * 4 + t] = *(const short8v*)(pK + ks * 65536 + t * 32);

  auto body = [&](short8v (&kc)[8], short8v (&kn)[8], int it) {
    // V for this iter: issue first (covered by QK + softmax)
    short8v vv[8];
    #pragma unroll
    for (int ks = 0; ks < 2; ++ks)
      #pragma unroll
      for (int kk = 0; kk < 2; ++kk) {
        vv[ks * 4 + kk * 2 + 0] = *(const short8v*)(pV0 + it * 128 + ks * 64 + kk * 32);
        vv[ks * 4 + kk * 2 + 1] = *(const short8v*)(pV1 + it * 128 + ks * 64 + kk * 32);
      }
    const int itn = (it + 1) & 15;           // last iter: harmless wrap load (unused)
    #pragma unroll
    for (int ks = 0; ks < 2; ++ks) {
      // S^T = K Q^T : lane holds S[key=(r&3)+8(r>>2)+4hi][q=q31] (exp2 domain)
      f32x16 s0, s1;
      #pragma unroll
      for (int r = 0; r < 16; ++r) { s0[r] = 0.f; s1[r] = 0.f; }
      __builtin_amdgcn_s_setprio(1);
      s0 = MFMA32(kc[ks * 4 + 0], qf[0], s0, 0, 0, 0);
      s1 = MFMA32(kc[ks * 4 + 1], qf[1], s1, 0, 0, 0);
      s0 = MFMA32(kc[ks * 4 + 2], qf[2], s0, 0, 0, 0);
      s1 = MFMA32(kc[ks * 4 + 3], qf[3], s1, 0, 0, 0);
      __builtin_amdgcn_s_setprio(0);
      if (ks == 0) {                          // prefetch next K tile into kn
        #pragma unroll
        for (int j = 0; j < 2; ++j)
          #pragma unroll
          for (int t = 0; t < 4; ++t)
            kn[j * 4 + t] = *(const short8v*)(pK + (size_t)itn * 131072 + j * 65536 + t * 32);
      }
      float sc[16];
      #pragma unroll
      for (int r = 0; r < 16; ++r) sc[r] = s0[r] + s1[r];

      // tile max: depth-4 tree + partner half
      float a0 = fmaxf(sc[0], sc[1]), a1 = fmaxf(sc[2], sc[3]);
      float a2 = fmaxf(sc[4], sc[5]), a3 = fmaxf(sc[6], sc[7]);
      float a4 = fmaxf(sc[8], sc[9]), a5 = fmaxf(sc[10], sc[11]);
      float a6 = fmaxf(sc[12], sc[13]), a7 = fmaxf(sc[14], sc[15]);
      float b0 = fmaxf(a0, a1), b1 = fmaxf(a2, a3);
      float b2 = fmaxf(a4, a5), b3 = fmaxf(a6, a7);
      float tmax = fmaxf(fmaxf(b0, b1), fmaxf(b2, b3));
      tmax = fmaxf(tmax, __shfl_xor(tmax, 32, 64));

      if (!__all(tmax <= m_s + 11.0f)) {     // defer-max (T13)
        const float mn = fmaxf(m_s, tmax);
        const float al = __builtin_amdgcn_exp2f(m_s - mn);
        m_s = mn;
        l_s *= al;
        #pragma unroll
        for (int r = 0; r < 16; ++r) {
          const float ar = __shfl(al, (r & 3) + 8 * (r >> 2) + hi4, 64);
          accO[0][r] *= ar;
          accO[1][r] *= ar;
        }
      }

      // P = exp2(S - m); pack to bf16 A-frags in registers (T12)
      float p[16];
      #pragma unroll
      for (int r = 0; r < 16; ++r) p[r] = __builtin_amdgcn_exp2f(sc[r] - m_s);
      float q0 = (p[0] + p[1]) + (p[2] + p[3]);
      float q1 = (p[4] + p[5]) + (p[6] + p[7]);
      float q2 = (p[8] + p[9]) + (p[10] + p[11]);
      float q3 = (p[12] + p[13]) + (p[14] + p[15]);
      float rs = (q0 + q1) + (q2 + q3);
      rs += __shfl_xor(rs, 32, 64);
      l_s += rs;

      u32 c0, c1, c2, c3, c4, c5, c6, c7;
      asm("v_cvt_pk_bf16_f32 %0, %1, %2" : "=v"(c0) : "v"(p[0]), "v"(p[1]));
      asm("v_cvt_pk_bf16_f32 %0, %1, %2" : "=v"(c1) : "v"(p[2]), "v"(p[3]));
      asm("v_cvt_pk_bf16_f32 %0, %1, %2" : "=v"(c2) : "v"(p[4]), "v"(p[5]));
      asm("v_cvt_pk_bf16_f32 %0, %1, %2" : "=v"(c3) : "v"(p[6]), "v"(p[7]));
      asm("v_cvt_pk_bf16_f32 %0, %1, %2" : "=v"(c4) : "v"(p[8]), "v"(p[9]));
      asm("v_cvt_pk_bf16_f32 %0, %1, %2" : "=v"(c5) : "v"(p[10]), "v"(p[11]));
      asm("v_cvt_pk_bf16_f32 %0, %1, %2" : "=v"(c6) : "v"(p[12]), "v"(p[13]));
      asm("v_cvt_pk_bf16_f32 %0, %1, %2" : "=v"(c7) : "v"(p[14]), "v"(p[15]));
      asm volatile("v_permlane32_swap_b32 %0, %1" : "+v"(c0), "+v"(c2));
      asm volatile("v_permlane32_swap_b32 %0, %1" : "+v"(c1), "+v"(c3));
      asm volatile("v_permlane32_swap_b32 %0, %1" : "+v"(c4), "+v"(c6));
      asm volatile("v_permlane32_swap_b32 %0, %1" : "+v"(c5), "+v"(c7));
      union { u32 u[4]; short8v s; } pa0, pa1;
      pa0.u[0] = c0; pa0.u[1] = c1; pa0.u[2] = c2; pa0.u[3] = c3;
      pa1.u[0] = c4; pa1.u[1] = c5; pa1.u[2] = c6; pa1.u[3] = c7;

      // O += P V
      #pragma unroll
      for (int kk = 0; kk < 2; ++kk) {
        const short8v pa = kk ? pa1.s : pa0.s;
        const short8v vb0 = vv[ks * 4 + kk * 2 + 0];
        const short8v vb1 = vv[ks * 4 + kk * 2 + 1];
        __builtin_amdgcn_s_setprio(1);
        accO[0] = MFMA32(pa, vb0, accO[0], 0, 0, 0);
        accO[1] = MFMA32(pa, vb1, accO[1], 0, 0, 0);
        __builtin_amdgcn_s_setprio(0);
      }
    }
  };

  for (int it2 = 0; it2 < 8; ++it2) {
    body(kA, kB, it2 * 2);
    body(kB, kA, it2 * 2 + 1);
  }

  // ---- split-K merge: exchange (m,l), then alpha-scaled O add via LDS ----
  float* mlds = (float*)&smem[16384];        // m: [g*2+kh][32], l at +128 floats
  if (l < 32) {
    mlds[(g * 2 + kh) * 32 + l] = m_s;
    mlds[128 + (g * 2 + kh) * 32 + l] = l_s;
  }
  __syncthreads();
  const float m0 = mlds[(g * 2 + 0) * 32 + q31];
  const float m1 = mlds[(g * 2 + 1) * 32 + q31];
  const float l0 = mlds[128 + (g * 2 + 0) * 32 + q31];
  const float l1 = mlds[128 + (g * 2 + 1) * 32 + q31];
  const float M = fmaxf(m0, m1);
  const float a0 = __builtin_amdgcn_exp2f(m0 - M);
  const float a1 = __builtin_amdgcn_exp2f(m1 - M);
  const float linv = 1.f / (l0 * a0 + l1 * a1);
  const float aown = kh ? a1 : a0;
  float* obuf = (float*)&smem[0];            // [g][32 q][64 d]
  if (kh == 1) {
    #pragma unroll
    for (int r = 0; r < 16; ++r) {
      const int qr = (r & 3) + 8 * (r >> 2) + hi4;
      const float ar = __shfl(aown, qr, 64);
      obuf[(g * 32 + qr) * 64 + q31] = accO[0][r] * ar;
      obuf[(g * 32 + qr) * 64 + 32 + q31] = accO[1][r] * ar;
    }
  }
  __syncthreads();
  if (kh == 0) {
    #pragma unroll
    for (int r = 0; r < 16; ++r) {
      const int qr = (r & 3) + 8 * (r >> 2) + hi4;
      const float ar = __shfl(aown, qr, 64);
      const float li = __shfl(linv, qr, 64);
      const int row = qt * 64 + g * 32 + qr;
      const float v0 = (accO[0][r] * ar + obuf[(g * 32 + qr) * 64 + q31]) * li;
      const float v1 = (accO[1][r] * ar + obuf[(g * 32 + qr) * 64 + 32 + q31]) * li;
      og[(size_t)row * DIM + h * HD + q31] = f2b(v0);
      og[(size_t)row * DIM + h * HD + 32 + q31] = f2b(v1);
    }
  }
}

// ---------- LayerNorm + per-modality affine + scatter ----------
__global__ __launch_bounds__(256) void ln_scatter(const float* __restrict__ o,
                                                  const float* __restrict__ lnw,
                                                  const float* __restrict__ lnb,
                                                  const int* __restrict__ perm,
                                                  const int* __restrict__ cntp,
                                                  float* __restrict__ out) {
  const int i = blockIdx.x;
  const int tid = threadIdx.x, w = tid >> 6, l = tid & 63;
  const int mod = (i < cntp[0]) ? 0 : 1;
  float4 v = ((const float4*)(o + (size_t)i * DIM))[tid];
  float s = v.x + v.y + v.z + v.w;
  float ss = v.x * v.x + v.y * v.y + v.z * v.z + v.w * v.w;
  #pragma unroll
  for (int off = 1; off < 64; off <<= 1) {
    s += __shfl_xor(s, off, 64);
    ss += __shfl_xor(ss, off, 64);
  }
  __shared__ float rs4[4], rss4[4];
  if (l == 0) { rs4[w] = s; rss4[w] = ss; }
  __syncthreads();
  const float st = rs4[0] + rs4[1] + rs4[2] + rs4[3];
  const float sst = rss4[0] + rss4[1] + rss4[2] + rss4[3];
  const float mu = st * (1.f / DIM);
  const float var = sst * (1.f / DIM) - mu * mu;
  const float rstd = rsqrtf(var + 1e-5f);
  const int drow = perm[i];
  float4 g = ((const float4*)(lnw + (size_t)mod * DIM))[tid];
  float4 b = ((const float4*)(lnb + (size_t)mod * DIM))[tid];
  float4 rr;
  rr.x = (v.x - mu) * rstd * g.x + b.x;
  rr.y = (v.y - mu) * rstd * g.y + b.y;
  rr.z = (v.z - mu) * rstd * g.z + b.z;
  rr.w = (v.w - mu) * rstd * g.w + b.w;
  ((float4*)(out + (size_t)drow * DIM))[tid] = rr;
}

// ---------- launch ----------
extern "C" void kernel_launch(void* const* d_in, const int* in_sizes, int n_in,
                              void* d_out, int out_size, void* d_ws, size_t ws_size,
                              hipStream_t stream) {
  const float* x = (const float*)d_in[0];
  const void* masks = d_in[1];
  const float* wq = (const float*)d_in[3];
  const float* wk = (const float*)d_in[4];
  const float* wv = (const float*)d_in[5];
  const float* wo = (const float*)d_in[6];
  const float* lnw = (const float*)d_in[7];
  const float* lnb = (const float*)d_in[8];

  char* ws = (char*)d_ws;
  int* perm = (int*)(ws + OFF_PERM);
  int* cnt = (int*)(ws + OFF_CNT);
  u16* xpb = (u16*)(ws + OFF_XPB);
  u16* wT = (u16*)(ws + OFF_WT);
  u16* q = (u16*)(ws + OFF_Q);
  u16* k = (u16*)(ws + OFF_K);
  u16* v = (u16*)(ws + OFF_V);
  u16* vT = (u16*)(ws + OFF_VT);
  u16* at = (u16*)(ws + OFF_AT);
  float* o = (float*)(ws + OFF_O);
  float* out = (float*)d_out;

  prep_kernel<<<1, 256, 0, stream>>>(masks, perm, cnt);
  gather_cast<<<N_TOK, 256, 0, stream>>>(x, perm, xpb);
  wcast<<<dim3(32, 32, 8), dim3(32, 8), 0, stream>>>(wq, wk, wv, wo, wT);
  gemm_exp<0><<<dim3(8, 32, 3), 256, 0, stream>>>(xpb, wT, 0, QSCALE, q, k, v, cnt);
  vtrans<<<dim3(64, 2, 16), dim3(32, 8), 0, stream>>>(v, vT);
  attn_fwd<<<dim3(32, 16), 256, 0, stream>>>(q, k, vT, at);
  gemm_exp<1><<<dim3(8, 32, 1), 256, 0, stream>>>(at, wT, 3, 1.0f, o, o, o, cnt);
  ln_scatter<<<N_TOK, 256, 0, stream>>>(o, lnw, lnb, perm, cnt, out);
}

// Round 5
// 109.397 us; speedup vs baseline: 1.2749x; 1.2749x over previous
//
#include <hip/hip_runtime.h>

typedef __attribute__((ext_vector_type(8))) short short8v;
typedef __attribute__((ext_vector_type(4))) float f32x4;
typedef __attribute__((ext_vector_type(16))) float f32x16;
typedef unsigned short u16;
typedef unsigned int u32;

#define MFMA __builtin_amdgcn_mfma_f32_16x16x32_bf16
#define MFMA32 __builtin_amdgcn_mfma_f32_32x32x16_bf16

// ---------- helpers ----------
__device__ __forceinline__ u16 f2b(float f) {
  u32 u = __float_as_uint(f);
  u = (u + 0x7FFFu + ((u >> 16) & 1u)) >> 16;
  return (u16)u;
}
__device__ __forceinline__ float b2f(u16 b) {
  return __uint_as_float(((u32)b) << 16);
}
__device__ __forceinline__ void g2l16(const void* g, void* l) {
  __builtin_amdgcn_global_load_lds(
      (const __attribute__((address_space(1))) unsigned int*)g,
      (__attribute__((address_space(3))) unsigned int*)l, 16, 0, 0);
}

// sizes
#define N_TOK 2048
#define DIM 1024
#define NH 16
#define HD 64

// Q pre-scale: hd^-0.5 * log2(e)  (softmax runs in exp2 domain)
#define QSCALE 0.18033688011112042f

// workspace layout (bytes)
#define OFF_PERM 0
#define OFF_CNT 8192
#define OFF_XPB 16384
#define OFF_WT (OFF_XPB + 4194304)          // 16 MB: [tensor][expert][1024][1024] bf16, WT[n][k]
#define OFF_Q (OFF_WT + 16777216)
#define OFF_K (OFF_Q + 4194304)
#define OFF_V (OFF_K + 4194304)
#define OFF_VT (OFF_V + 4194304)            // [16][64][2048] bf16
#define OFF_AT (OFF_VT + 4194304)
#define OFF_O (OFF_AT + 4194304)            // f32 [2048][1024]

// ---------- prep: modality ids, stable partition perm, cnt0 ----------
__global__ __launch_bounds__(256) void prep_kernel(const void* __restrict__ masks,
                                                   int* __restrict__ perm,
                                                   int* __restrict__ cnt) {
  const int tid = threadIdx.x;
  __shared__ u32 red[256];
  __shared__ int scan[256];
  const u32* mw = (const u32*)masks;
  u32 mx = 0;
  for (int i = tid; i < 1024; i += 256) { u32 v = mw[i]; mx = mx > v ? mx : v; }
  red[tid] = mx;
  __syncthreads();
  for (int off = 128; off; off >>= 1) {
    if (tid < off) red[tid] = red[tid] > red[tid + off] ? red[tid] : red[tid + off];
    __syncthreads();
  }
  const bool isbyte = red[0] > 1u;
  int md[8];
  int c0loc = 0;
  #pragma unroll
  for (int j = 0; j < 8; ++j) {
    const int n = tid * 8 + j;
    int m1;
    if (isbyte) m1 = ((const unsigned char*)masks)[N_TOK + n] != 0;
    else        m1 = mw[N_TOK + n] != 0;
    md[j] = m1;
    c0loc += (m1 == 0);
  }
  scan[tid] = c0loc;
  __syncthreads();
  for (int off = 1; off < 256; off <<= 1) {
    int v = (tid >= off) ? scan[tid - off] : 0;
    __syncthreads();
    scan[tid] += v;
    __syncthreads();
  }
  const int incl = scan[tid];
  const int total0 = scan[255];
  const int excl0 = incl - c0loc;
  int p0 = excl0;
  int p1 = total0 + (tid * 8 - excl0);
  #pragma unroll
  for (int j = 0; j < 8; ++j) {
    const int n = tid * 8 + j;
    if (!md[j]) perm[p0++] = n; else perm[p1++] = n;
  }
  if (tid == 0) cnt[0] = total0;
}

// ---------- gather + cast x -> xp bf16 ----------
__global__ __launch_bounds__(256) void gather_cast(const float* __restrict__ x,
                                                   const int* __restrict__ perm,
                                                   u16* __restrict__ xpb) {
  const int i = blockIdx.x;
  const int src = perm[i];
  const int tid = threadIdx.x;
  float4 v = ((const float4*)(x + (size_t)src * DIM))[tid];
  ushort4 o;
  o.x = f2b(v.x); o.y = f2b(v.y); o.z = f2b(v.z); o.w = f2b(v.w);
  ((ushort4*)(xpb + (size_t)i * DIM))[tid] = o;
}

// ---------- weight transpose-cast: W[k][n] f32 -> WT[n][k] bf16 ----------
__global__ __launch_bounds__(256) void wcast(const float* __restrict__ wq,
                                             const float* __restrict__ wk,
                                             const float* __restrict__ wv,
                                             const float* __restrict__ wo,
                                             u16* __restrict__ wT) {
  const int mat = blockIdx.z;               // tensor*2 + expert
  const int tensor = mat >> 1, expert = mat & 1;
  const float* src = (tensor == 0) ? wq : (tensor == 1) ? wk : (tensor == 2) ? wv : wo;
  src += (size_t)expert * (1 << 20);
  u16* dst = wT + ((size_t)mat << 20);
  const int k0 = blockIdx.x * 32, n0 = blockIdx.y * 32;
  const int tx = threadIdx.x, ty = threadIdx.y;
  __shared__ float t[32][33];
  #pragma unroll
  for (int r = 0; r < 4; ++r)
    t[ty + 8 * r][tx] = src[(size_t)(k0 + ty + 8 * r) * DIM + n0 + tx];
  __syncthreads();
  #pragma unroll
  for (int r = 0; r < 4; ++r)
    dst[(size_t)(n0 + ty + 8 * r) * DIM + k0 + tx] = f2b(t[tx][ty + 8 * r]);
}

// ---------- V transpose per head: v[n][h*64+d] -> vT[h][d][n] ----------
__global__ __launch_bounds__(256) void vtrans(const u16* __restrict__ v,
                                              u16* __restrict__ vT) {
  const int h = blockIdx.z;
  const int n0 = blockIdx.x * 32, d0 = blockIdx.y * 32;
  const int tx = threadIdx.x, ty = threadIdx.y;
  __shared__ u16 t[32][33];
  #pragma unroll
  for (int r = 0; r < 4; ++r)
    t[ty + 8 * r][tx] = v[(size_t)(n0 + ty + 8 * r) * DIM + h * HD + d0 + tx];
  __syncthreads();
  #pragma unroll
  for (int r = 0; r < 4; ++r)
    vT[(size_t)(h * HD + d0 + ty + 8 * r) * N_TOK + n0 + tx] = t[tx][ty + 8 * r];
}

// ---------- expert GEMM ----------
template <int OUTF32>
__global__ __launch_bounds__(256) void gemm_exp(const u16* __restrict__ X,
                                                const u16* __restrict__ WTall,
                                                int tensor0, float scale0,
                                                void* __restrict__ o0,
                                                void* __restrict__ o1,
                                                void* __restrict__ o2,
                                                const int* __restrict__ cntp) {
  const int z = blockIdx.z;
  const int e = blockIdx.y >> 4;
  const int mt = blockIdx.y & 15;
  const int c0 = cntp[0];
  const int lo = e ? c0 : 0;
  const int hi = e ? N_TOK : c0;
  const int rb = mt * 128;
  if (rb >= hi || rb + 128 <= lo) return;
  const int cb = blockIdx.x * 128;
  void* OUT = (z == 0) ? o0 : (z == 1) ? o1 : o2;
  const u16* W = WTall + ((size_t)((tensor0 + z) * 2 + e) << 20);
  const float scl = (z == 0) ? scale0 : 1.f;

  const int tid = threadIdx.x;
  const int w = tid >> 6, l = tid & 63, lg = l >> 4, ln = l & 15;
  const int wm = (w >> 1) * 64, wn = (w & 1) * 64;

  __shared__ __align__(16) char smem[32768];

  auto stage = [&](int it, int b_) {
    const int k0b = it * 64;
    #pragma unroll
    for (int c = 0; c < 2; ++c) {
      const int lb = (tid + c * 256) * 16;
      const int row = lb >> 6, colb = lb & 63;
      g2l16((const char*)X + (size_t)(rb + row) * 2048 + k0b + colb,
            &smem[b_ * 16384 + lb]);
      g2l16((const char*)W + (size_t)(cb + row) * 2048 + k0b + colb,
            &smem[b_ * 16384 + 8192 + lb]);
    }
  };

  f32x4 acc[4][4];
  #pragma unroll
  for (int i = 0; i < 4; ++i)
    #pragma unroll
    for (int j = 0; j < 4; ++j) acc[i][j] = (f32x4){0.f, 0.f, 0.f, 0.f};

  stage(0, 0);
  __syncthreads();
  for (int it = 0; it < 32; ++it) {
    const int b_ = it & 1;
    if (it < 31) stage(it + 1, b_ ^ 1);
    short8v a[4], bb[4];
    #pragma unroll
    for (int mi = 0; mi < 4; ++mi)
      a[mi] = *(const short8v*)&smem[b_ * 16384 + (wm + mi * 16 + ln) * 64 + lg * 16];
    #pragma unroll
    for (int ni = 0; ni < 4; ++ni)
      bb[ni] = *(const short8v*)&smem[b_ * 16384 + 8192 + (wn + ni * 16 + ln) * 64 + lg * 16];
    __builtin_amdgcn_s_setprio(1);
    #pragma unroll
    for (int mi = 0; mi < 4; ++mi)
      #pragma unroll
      for (int ni = 0; ni < 4; ++ni)
        acc[mi][ni] = MFMA(a[mi], bb[ni], acc[mi][ni], 0, 0, 0);
    __builtin_amdgcn_s_setprio(0);
    __syncthreads();
  }

  #pragma unroll
  for (int mi = 0; mi < 4; ++mi) {
    #pragma unroll
    for (int r = 0; r < 4; ++r) {
      const int row = rb + wm + mi * 16 + lg * 4 + r;
      if (row >= lo && row < hi) {
        #pragma unroll
        for (int ni = 0; ni < 4; ++ni) {
          const int col = cb + wn + ni * 16 + ln;
          const float vv = acc[mi][ni][r] * scl;
          if (OUTF32) ((float*)OUT)[(size_t)row * DIM + col] = vv;
          else ((u16*)OUT)[(size_t)row * DIM + col] = f2b(vv);
        }
      }
    }
  }
}

// ---------- flash attention: 32x32x16, LDS-staged K/V, in-register P, 64q/wave ----------
// grid: 256 blocks (16 qtiles x 16 heads, XCD-swizzled). Block = 8 waves:
// wave w -> qgroup g=w&1 (64 q rows, 2 B-sets) x key-quarter kq=w>>1 (512 keys,
// 8 iters of 64). LDS: 4 streams x dbuf x (K 8KB + V 8KB) = 128KB.
__global__ __launch_bounds__(512, 2) void attn_fwd(const u16* __restrict__ qg,
                                                   const u16* __restrict__ kg,
                                                   const u16* __restrict__ vTg,
                                                   u16* __restrict__ og) {
  const int bid = blockIdx.x;
  const int wg = (bid & 7) * 32 + (bid >> 3);   // bijective XCD swizzle (256 = 8*32)
  const int qt = wg & 15, h = wg >> 4;
  const int tid = threadIdx.x, w = tid >> 6, l = tid & 63;
  const int g = w & 1, kq = w >> 1;
  const int q31 = l & 31, hi = l >> 5;
  const int hi16 = hi * 16, hi4 = hi * 4;

  __shared__ __align__(16) char smem[131072];

  auto stage = [&](int it, int b_) {
    #pragma unroll
    for (int c = 0; c < 8; ++c) {
      const int j = tid + c * 512;             // 0..4095 -> 64KB
      const int s_ = j >> 10;                  // stream = key-quarter
      const int rem = j & 1023;
      const int isV = rem >> 9;
      const int cc = rem & 511;
      const int r = cc >> 3, c16 = cc & 7;
      const int colb = (c16 * 16) ^ ((r & 7) << 4);   // pre-swizzled source
      const char* src;
      if (isV)
        src = (const char*)vTg + (size_t)(h * HD + r) * 4096 + (s_ * 512 + it * 64) * 2 + colb;
      else
        src = (const char*)kg + (size_t)(s_ * 512 + it * 64 + r) * 2048 + h * 128 + colb;
      g2l16(src, &smem[s_ * 32768 + b_ * 16384 + isV * 8192 + cc * 16]);
    }
  };
  auto ldf = [&](int base, int row, int colb) -> short8v {
    return *(const short8v*)&smem[base + row * 128 + (colb ^ ((row & 7) << 4))];
  };

  // Q fragments (B-operand, 2 sets of 32 q-cols); one-time strided loads
  const char* qb = (const char*)qg + (size_t)(qt * 128 + g * 64 + q31) * 2048 + h * 128;
  short8v qf0[4], qf1[4];
  #pragma unroll
  for (int t = 0; t < 4; ++t) {
    qf0[t] = *(const short8v*)(qb + t * 32 + hi16);
    qf1[t] = *(const short8v*)(qb + 65536 + t * 32 + hi16);
  }

  stage(0, 0);
  __syncthreads();

  float m0 = -1e30f, l0 = 0.f, m1 = -1e30f, l1 = 0.f;
  f32x16 acc00, acc01, acc10, acc11;          // [qset][dset]
  #pragma unroll
  for (int r = 0; r < 16; ++r) { acc00[r] = 0.f; acc01[r] = 0.f; acc10[r] = 0.f; acc11[r] = 0.f; }

  // softmax + PV for one q-set; builds P A-frags in registers (T12) and MFMAs
  auto softmax_pv = [&](f32x16& s_, float& m_s, float& l_s,
                        f32x16& accA, f32x16& accB, const short8v vf[2][2]) {
    float tmax = s_[0];
    #pragma unroll
    for (int r = 1; r < 16; ++r) tmax = fmaxf(tmax, s_[r]);
    tmax = fmaxf(tmax, __shfl_xor(tmax, 32, 64));
    if (!__all(tmax <= m_s + 11.0f)) {        // defer-max (T13)
      const float mn = fmaxf(m_s, tmax);
      const float al = __builtin_amdgcn_exp2f(m_s - mn);
      m_s = mn;
      l_s *= al;
      #pragma unroll
      for (int r = 0; r < 16; ++r) {
        const float ar = __shfl(al, (r & 3) + 8 * (r >> 2) + hi4, 64);
        accA[r] *= ar;
        accB[r] *= ar;
      }
    }
    float p[16];
    #pragma unroll
    for (int r = 0; r < 16; ++r) p[r] = __builtin_amdgcn_exp2f(s_[r] - m_s);
    float rs = ((p[0] + p[1]) + (p[2] + p[3])) + ((p[4] + p[5]) + (p[6] + p[7])) +
               (((p[8] + p[9]) + (p[10] + p[11])) + ((p[12] + p[13]) + (p[14] + p[15])));
    rs += __shfl_xor(rs, 32, 64);
    l_s += rs;

    u32 c0, c1, c2, c3, c4, c5, c6, c7;
    asm("v_cvt_pk_bf16_f32 %0, %1, %2" : "=v"(c0) : "v"(p[0]), "v"(p[1]));
    asm("v_cvt_pk_bf16_f32 %0, %1, %2" : "=v"(c1) : "v"(p[2]), "v"(p[3]));
    asm("v_cvt_pk_bf16_f32 %0, %1, %2" : "=v"(c2) : "v"(p[4]), "v"(p[5]));
    asm("v_cvt_pk_bf16_f32 %0, %1, %2" : "=v"(c3) : "v"(p[6]), "v"(p[7]));
    asm("v_cvt_pk_bf16_f32 %0, %1, %2" : "=v"(c4) : "v"(p[8]), "v"(p[9]));
    asm("v_cvt_pk_bf16_f32 %0, %1, %2" : "=v"(c5) : "v"(p[10]), "v"(p[11]));
    asm("v_cvt_pk_bf16_f32 %0, %1, %2" : "=v"(c6) : "v"(p[12]), "v"(p[13]));
    asm("v_cvt_pk_bf16_f32 %0, %1, %2" : "=v"(c7) : "v"(p[14]), "v"(p[15]));
    asm volatile("v_permlane32_swap_b32 %0, %1" : "+v"(c0), "+v"(c2));
    asm volatile("v_permlane32_swap_b32 %0, %1" : "+v"(c1), "+v"(c3));
    asm volatile("v_permlane32_swap_b32 %0, %1" : "+v"(c4), "+v"(c6));
    asm volatile("v_permlane32_swap_b32 %0, %1" : "+v"(c5), "+v"(c7));
    union { u32 u[4]; short8v s; } pa0, pa1;
    pa0.u[0] = c0; pa0.u[1] = c1; pa0.u[2] = c2; pa0.u[3] = c3;
    pa1.u[0] = c4; pa1.u[1] = c5; pa1.u[2] = c6; pa1.u[3] = c7;
    __builtin_amdgcn_s_setprio(1);
    accA = MFMA32(pa0.s, vf[0][0], accA, 0, 0, 0);
    accB = MFMA32(pa0.s, vf[0][1], accB, 0, 0, 0);
    accA = MFMA32(pa1.s, vf[1][0], accA, 0, 0, 0);
    accB = MFMA32(pa1.s, vf[1][1], accB, 0, 0, 0);
    __builtin_amdgcn_s_setprio(0);
  };

  for (int it = 0; it < 8; ++it) {
    const int b_ = it & 1;
    if (it < 7) stage(it + 1, b_ ^ 1);
    const int Kb = kq * 32768 + b_ * 16384;
    const int Vb = Kb + 8192;

    #pragma unroll
    for (int ks = 0; ks < 2; ++ks) {
      short8v kf[4];
      #pragma unroll
      for (int t = 0; t < 4; ++t) kf[t] = ldf(Kb, ks * 32 + q31, t * 32 + hi16);
      short8v vf[2][2];
      #pragma unroll
      for (int kk = 0; kk < 2; ++kk)
        #pragma unroll
        for (int ds = 0; ds < 2; ++ds)
          vf[kk][ds] = ldf(Vb, ds * 32 + q31, ks * 64 + kk * 32 + hi16);

      f32x16 s0, s1;
      #pragma unroll
      for (int r = 0; r < 16; ++r) { s0[r] = 0.f; s1[r] = 0.f; }
      __builtin_amdgcn_s_setprio(1);
      s0 = MFMA32(kf[0], qf0[0], s0, 0, 0, 0);
      s1 = MFMA32(kf[0], qf1[0], s1, 0, 0, 0);
      s0 = MFMA32(kf[1], qf0[1], s0, 0, 0, 0);
      s1 = MFMA32(kf[1], qf1[1], s1, 0, 0, 0);
      s0 = MFMA32(kf[2], qf0[2], s0, 0, 0, 0);
      s1 = MFMA32(kf[2], qf1[2], s1, 0, 0, 0);
      s0 = MFMA32(kf[3], qf0[3], s0, 0, 0, 0);
      s1 = MFMA32(kf[3], qf1[3], s1, 0, 0, 0);
      __builtin_amdgcn_s_setprio(0);

      softmax_pv(s0, m0, l0, acc00, acc01, vf);
      softmax_pv(s1, m1, l1, acc10, acc11, vf);
    }
    __syncthreads();
  }
  __syncthreads();   // streams dead; LDS reused for merge

  // ---- 4-way split-K merge in LDS ----
  float* mm = (float*)&smem[98304];            // m[g][set][kq][32], l at +512 floats
  if (l < 32) {
    mm[((g * 2 + 0) * 4 + kq) * 32 + l] = m0;
    mm[((g * 2 + 1) * 4 + kq) * 32 + l] = m1;
    mm[512 + ((g * 2 + 0) * 4 + kq) * 32 + l] = l0;
    mm[512 + ((g * 2 + 1) * 4 + kq) * 32 + l] = l1;
  }
  __syncthreads();
  float al0, al1, li0, li1;
  #pragma unroll
  for (int set = 0; set < 2; ++set) {
    const int base = (g * 2 + set) * 4;
    float M = mm[(base + 0) * 32 + q31];
    M = fmaxf(M, mm[(base + 1) * 32 + q31]);
    M = fmaxf(M, mm[(base + 2) * 32 + q31]);
    M = fmaxf(M, mm[(base + 3) * 32 + q31]);
    float L = 0.f;
    #pragma unroll
    for (int j = 0; j < 4; ++j)
      L += mm[512 + (base + j) * 32 + q31] *
           __builtin_amdgcn_exp2f(mm[(base + j) * 32 + q31] - M);
    const float mo = set ? m1 : m0;
    const float a = __builtin_amdgcn_exp2f(mo - M);
    const float li = 1.f / L;
    if (set) { al1 = a; li1 = li; } else { al0 = a; li0 = li; }
  }

  float* obuf = (float*)&smem[g * 16384];      // [64 q][64 d] f32 per qgroup
  #pragma unroll
  for (int round = 3; round >= 0; --round) {
    if (kq == round) {
      #pragma unroll
      for (int set = 0; set < 2; ++set) {
        const float alS = set ? al1 : al0;
        const float liS = set ? li1 : li0;
        const f32x16& aA = set ? acc10 : acc00;
        const f32x16& aB = set ? acc11 : acc01;
        #pragma unroll
        for (int r = 0; r < 16; ++r) {
          const int qr = (r & 3) + 8 * (r >> 2) + hi4;
          const float ar = __shfl(alS, qr, 64);
          float* p0 = &obuf[(set * 32 + qr) * 64 + q31];
          float* p1 = &obuf[(set * 32 + qr) * 64 + 32 + q31];
          if (round == 3) {
            *p0 = aA[r] * ar;
            *p1 = aB[r] * ar;
          } else if (round > 0) {
            *p0 += aA[r] * ar;
            *p1 += aB[r] * ar;
          } else {
            const float li = __shfl(liS, qr, 64);
            const int row = qt * 128 + g * 64 + set * 32 + qr;
            og[(size_t)row * DIM + h * HD + q31] = f2b((aA[r] * ar + *p0) * li);
            og[(size_t)row * DIM + h * HD + 32 + q31] = f2b((aB[r] * ar + *p1) * li);
          }
        }
      }
    }
    __syncthreads();
  }
}

// ---------- LayerNorm + per-modality affine + scatter ----------
__global__ __launch_bounds__(256) void ln_scatter(const float* __restrict__ o,
                                                  const float* __restrict__ lnw,
                                                  const float* __restrict__ lnb,
                                                  const int* __restrict__ perm,
                                                  const int* __restrict__ cntp,
                                                  float* __restrict__ out) {
  const int i = blockIdx.x;
  const int tid = threadIdx.x, w = tid >> 6, l = tid & 63;
  const int mod = (i < cntp[0]) ? 0 : 1;
  float4 v = ((const float4*)(o + (size_t)i * DIM))[tid];
  float s = v.x + v.y + v.z + v.w;
  float ss = v.x * v.x + v.y * v.y + v.z * v.z + v.w * v.w;
  #pragma unroll
  for (int off = 1; off < 64; off <<= 1) {
    s += __shfl_xor(s, off, 64);
    ss += __shfl_xor(ss, off, 64);
  }
  __shared__ float rs4[4], rss4[4];
  if (l == 0) { rs4[w] = s; rss4[w] = ss; }
  __syncthreads();
  const float st = rs4[0] + rs4[1] + rs4[2] + rs4[3];
  const float sst = rss4[0] + rss4[1] + rss4[2] + rss4[3];
  const float mu = st * (1.f / DIM);
  const float var = sst * (1.f / DIM) - mu * mu;
  const float rstd = rsqrtf(var + 1e-5f);
  const int drow = perm[i];
  float4 g = ((const float4*)(lnw + (size_t)mod * DIM))[tid];
  float4 b = ((const float4*)(lnb + (size_t)mod * DIM))[tid];
  float4 rr;
  rr.x = (v.x - mu) * rstd * g.x + b.x;
  rr.y = (v.y - mu) * rstd * g.y + b.y;
  rr.z = (v.z - mu) * rstd * g.z + b.z;
  rr.w = (v.w - mu) * rstd * g.w + b.w;
  ((float4*)(out + (size_t)drow * DIM))[tid] = rr;
}

// ---------- launch ----------
extern "C" void kernel_launch(void* const* d_in, const int* in_sizes, int n_in,
                              void* d_out, int out_size, void* d_ws, size_t ws_size,
                              hipStream_t stream) {
  const float* x = (const float*)d_in[0];
  const void* masks = d_in[1];
  const float* wq = (const float*)d_in[3];
  const float* wk = (const float*)d_in[4];
  const float* wv = (const float*)d_in[5];
  const float* wo = (const float*)d_in[6];
  const float* lnw = (const float*)d_in[7];
  const float* lnb = (const float*)d_in[8];

  char* ws = (char*)d_ws;
  int* perm = (int*)(ws + OFF_PERM);
  int* cnt = (int*)(ws + OFF_CNT);
  u16* xpb = (u16*)(ws + OFF_XPB);
  u16* wT = (u16*)(ws + OFF_WT);
  u16* q = (u16*)(ws + OFF_Q);
  u16* k = (u16*)(ws + OFF_K);
  u16* v = (u16*)(ws + OFF_V);
  u16* vT = (u16*)(ws + OFF_VT);
  u16* at = (u16*)(ws + OFF_AT);
  float* o = (float*)(ws + OFF_O);
  float* out = (float*)d_out;

  prep_kernel<<<1, 256, 0, stream>>>(masks, perm, cnt);
  gather_cast<<<N_TOK, 256, 0, stream>>>(x, perm, xpb);
  wcast<<<dim3(32, 32, 8), dim3(32, 8), 0, stream>>>(wq, wk, wv, wo, wT);
  gemm_exp<0><<<dim3(8, 32, 3), 256, 0, stream>>>(xpb, wT, 0, QSCALE, q, k, v, cnt);
  vtrans<<<dim3(64, 2, 16), dim3(32, 8), 0, stream>>>(v, vT);
  attn_fwd<<<256, 512, 0, stream>>>(q, k, vT, at);
  gemm_exp<1><<<dim3(8, 32, 1), 256, 0, stream>>>(at, wT, 3, 1.0f, o, o, o, cnt);
  ln_scatter<<<N_TOK, 256, 0, stream>>>(o, lnw, lnb, perm, cnt, out);
}

// Round 6
// 107.281 us; speedup vs baseline: 1.3000x; 1.0197x over previous
//
#include <hip/hip_runtime.h>

typedef __attribute__((ext_vector_type(8))) short short8v;
typedef __attribute__((ext_vector_type(4))) float f32x4;
typedef __attribute__((ext_vector_type(16))) float f32x16;
typedef unsigned short u16;
typedef unsigned int u32;

#define MFMA __builtin_amdgcn_mfma_f32_16x16x32_bf16
#define MFMA32 __builtin_amdgcn_mfma_f32_32x32x16_bf16

// ---------- helpers ----------
__device__ __forceinline__ u16 f2b(float f) {
  u32 u = __float_as_uint(f);
  u = (u + 0x7FFFu + ((u >> 16) & 1u)) >> 16;
  return (u16)u;
}
__device__ __forceinline__ float b2f(u16 b) {
  return __uint_as_float(((u32)b) << 16);
}
__device__ __forceinline__ void g2l16(const void* g, void* l) {
  __builtin_amdgcn_global_load_lds(
      (const __attribute__((address_space(1))) unsigned int*)g,
      (__attribute__((address_space(3))) unsigned int*)l, 16, 0, 0);
}

// sizes
#define N_TOK 2048
#define DIM 1024
#define NH 16
#define HD 64

// Q pre-scale: hd^-0.5 * log2(e)  (softmax runs in exp2 domain)
#define QSCALE 0.18033688011112042f

// workspace layout (bytes)
#define OFF_PERM 0
#define OFF_CNT 8192
#define OFF_XPB 16384
#define OFF_WT (OFF_XPB + 4194304)          // 16 MB: [tensor][expert][1024][1024] bf16, WT[n][k]
#define OFF_Q (OFF_WT + 16777216)
#define OFF_K (OFF_Q + 4194304)
#define OFF_V (OFF_K + 4194304)
#define OFF_VT (OFF_V + 4194304)            // [16][64][2048] bf16
#define OFF_AT (OFF_VT + 4194304)
#define OFF_O (OFF_AT + 4194304)            // f32 [2048][1024]
#define OFF_O2 (OFF_O + 8388608)            // f32 [2048][1024] split-K partial

// ---------- prep: modality ids, stable partition perm, cnt0 ----------
__global__ __launch_bounds__(256) void prep_kernel(const void* __restrict__ masks,
                                                   int* __restrict__ perm,
                                                   int* __restrict__ cnt) {
  const int tid = threadIdx.x;
  __shared__ u32 red[256];
  __shared__ int scan[256];
  const u32* mw = (const u32*)masks;
  u32 mx = 0;
  for (int i = tid; i < 1024; i += 256) { u32 v = mw[i]; mx = mx > v ? mx : v; }
  red[tid] = mx;
  __syncthreads();
  for (int off = 128; off; off >>= 1) {
    if (tid < off) red[tid] = red[tid] > red[tid + off] ? red[tid] : red[tid + off];
    __syncthreads();
  }
  const bool isbyte = red[0] > 1u;
  int md[8];
  int c0loc = 0;
  #pragma unroll
  for (int j = 0; j < 8; ++j) {
    const int n = tid * 8 + j;
    int m1;
    if (isbyte) m1 = ((const unsigned char*)masks)[N_TOK + n] != 0;
    else        m1 = mw[N_TOK + n] != 0;
    md[j] = m1;
    c0loc += (m1 == 0);
  }
  scan[tid] = c0loc;
  __syncthreads();
  for (int off = 1; off < 256; off <<= 1) {
    int v = (tid >= off) ? scan[tid - off] : 0;
    __syncthreads();
    scan[tid] += v;
    __syncthreads();
  }
  const int incl = scan[tid];
  const int total0 = scan[255];
  const int excl0 = incl - c0loc;
  int p0 = excl0;
  int p1 = total0 + (tid * 8 - excl0);
  #pragma unroll
  for (int j = 0; j < 8; ++j) {
    const int n = tid * 8 + j;
    if (!md[j]) perm[p0++] = n; else perm[p1++] = n;
  }
  if (tid == 0) cnt[0] = total0;
}

// ---------- gather + cast x -> xp bf16 ----------
__global__ __launch_bounds__(256) void gather_cast(const float* __restrict__ x,
                                                   const int* __restrict__ perm,
                                                   u16* __restrict__ xpb) {
  const int i = blockIdx.x;
  const int src = perm[i];
  const int tid = threadIdx.x;
  float4 v = ((const float4*)(x + (size_t)src * DIM))[tid];
  ushort4 o;
  o.x = f2b(v.x); o.y = f2b(v.y); o.z = f2b(v.z); o.w = f2b(v.w);
  ((ushort4*)(xpb + (size_t)i * DIM))[tid] = o;
}

// ---------- weight transpose-cast: W[k][n] f32 -> WT[n][k] bf16 ----------
__global__ __launch_bounds__(256) void wcast(const float* __restrict__ wq,
                                             const float* __restrict__ wk,
                                             const float* __restrict__ wv,
                                             const float* __restrict__ wo,
                                             u16* __restrict__ wT) {
  const int mat = blockIdx.z;               // tensor*2 + expert
  const int tensor = mat >> 1, expert = mat & 1;
  const float* src = (tensor == 0) ? wq : (tensor == 1) ? wk : (tensor == 2) ? wv : wo;
  src += (size_t)expert * (1 << 20);
  u16* dst = wT + ((size_t)mat << 20);
  const int k0 = blockIdx.x * 32, n0 = blockIdx.y * 32;
  const int tx = threadIdx.x, ty = threadIdx.y;
  __shared__ float t[32][33];
  #pragma unroll
  for (int r = 0; r < 4; ++r)
    t[ty + 8 * r][tx] = src[(size_t)(k0 + ty + 8 * r) * DIM + n0 + tx];
  __syncthreads();
  #pragma unroll
  for (int r = 0; r < 4; ++r)
    dst[(size_t)(n0 + ty + 8 * r) * DIM + k0 + tx] = f2b(t[tx][ty + 8 * r]);
}

// ---------- V transpose per head: v[n][h*64+d] -> vT[h][d][n] ----------
__global__ __launch_bounds__(256) void vtrans(const u16* __restrict__ v,
                                              u16* __restrict__ vT) {
  const int h = blockIdx.z;
  const int n0 = blockIdx.x * 32, d0 = blockIdx.y * 32;
  const int tx = threadIdx.x, ty = threadIdx.y;
  __shared__ u16 t[32][33];
  #pragma unroll
  for (int r = 0; r < 4; ++r)
    t[ty + 8 * r][tx] = v[(size_t)(n0 + ty + 8 * r) * DIM + h * HD + d0 + tx];
  __syncthreads();
  #pragma unroll
  for (int r = 0; r < 4; ++r)
    vT[(size_t)(h * HD + d0 + ty + 8 * r) * N_TOK + n0 + tx] = t[tx][ty + 8 * r];
}

// ---------- expert GEMM (optionally split-K over blockIdx.z) ----------
template <int OUTF32>
__global__ __launch_bounds__(256) void gemm_exp(const u16* __restrict__ X,
                                                const u16* __restrict__ WTall,
                                                int tensor0, float scale0,
                                                int split_k,
                                                void* __restrict__ o0,
                                                void* __restrict__ o1,
                                                void* __restrict__ o2,
                                                const int* __restrict__ cntp) {
  const int z = blockIdx.z;
  const int e = blockIdx.y >> 4;
  const int mt = blockIdx.y & 15;
  const int c0 = cntp[0];
  const int lo = e ? c0 : 0;
  const int hi = e ? N_TOK : c0;
  const int rb = mt * 128;
  if (rb >= hi || rb + 128 <= lo) return;
  const int cb = blockIdx.x * 128;
  int tensor, kstart, kiters;
  void* OUT;
  float scl;
  if (split_k) {            // z = K-half; tensor fixed
    tensor = tensor0; OUT = z ? o1 : o0; kstart = z * 16; kiters = 16; scl = 1.f;
  } else {                  // z = tensor index
    tensor = tensor0 + z; OUT = (z == 0) ? o0 : (z == 1) ? o1 : o2;
    kstart = 0; kiters = 32; scl = (z == 0) ? scale0 : 1.f;
  }
  const u16* W = WTall + ((size_t)(tensor * 2 + e) << 20);

  const int tid = threadIdx.x;
  const int w = tid >> 6, l = tid & 63, lg = l >> 4, ln = l & 15;
  const int wm = (w >> 1) * 64, wn = (w & 1) * 64;

  __shared__ __align__(16) char smem[32768];

  auto stage = [&](int it, int b_) {
    const int k0b = it * 64;
    #pragma unroll
    for (int c = 0; c < 2; ++c) {
      const int lb = (tid + c * 256) * 16;
      const int row = lb >> 6, colb = lb & 63;
      g2l16((const char*)X + (size_t)(rb + row) * 2048 + k0b + colb,
            &smem[b_ * 16384 + lb]);
      g2l16((const char*)W + (size_t)(cb + row) * 2048 + k0b + colb,
            &smem[b_ * 16384 + 8192 + lb]);
    }
  };

  f32x4 acc[4][4];
  #pragma unroll
  for (int i = 0; i < 4; ++i)
    #pragma unroll
    for (int j = 0; j < 4; ++j) acc[i][j] = (f32x4){0.f, 0.f, 0.f, 0.f};

  stage(kstart, 0);
  __syncthreads();
  for (int ii = 0; ii < kiters; ++ii) {
    const int b_ = ii & 1;
    if (ii < kiters - 1) stage(kstart + ii + 1, b_ ^ 1);
    short8v a[4], bb[4];
    #pragma unroll
    for (int mi = 0; mi < 4; ++mi)
      a[mi] = *(const short8v*)&smem[b_ * 16384 + (wm + mi * 16 + ln) * 64 + lg * 16];
    #pragma unroll
    for (int ni = 0; ni < 4; ++ni)
      bb[ni] = *(const short8v*)&smem[b_ * 16384 + 8192 + (wn + ni * 16 + ln) * 64 + lg * 16];
    __builtin_amdgcn_s_setprio(1);
    #pragma unroll
    for (int mi = 0; mi < 4; ++mi)
      #pragma unroll
      for (int ni = 0; ni < 4; ++ni)
        acc[mi][ni] = MFMA(a[mi], bb[ni], acc[mi][ni], 0, 0, 0);
    __builtin_amdgcn_s_setprio(0);
    __syncthreads();
  }

  #pragma unroll
  for (int mi = 0; mi < 4; ++mi) {
    #pragma unroll
    for (int r = 0; r < 4; ++r) {
      const int row = rb + wm + mi * 16 + lg * 4 + r;
      if (row >= lo && row < hi) {
        #pragma unroll
        for (int ni = 0; ni < 4; ++ni) {
          const int col = cb + wn + ni * 16 + ln;
          const float vv = acc[mi][ni][r] * scl;
          if (OUTF32) ((float*)OUT)[(size_t)row * DIM + col] = vv;
          else ((u16*)OUT)[(size_t)row * DIM + col] = f2b(vv);
        }
      }
    }
  }
}

// ---------- flash attention: 32x32x16, 4 waves/SIMD, KVBLK=32, in-register P ----------
// grid: 512 blocks (32 qtiles x 16 heads, XCD-swizzled); block = 8 waves:
// wave w -> qgroup g=w&1 (32 q rows) x key-quarter kq=w>>1 (512 keys, 16 iters of 32).
// LDS: 4 streams x dbuf x (K 4KB + V 4KB) = 64KB -> 2 blocks/CU -> 4 waves/SIMD.
__global__ __launch_bounds__(512, 4) void attn_fwd(const u16* __restrict__ qg,
                                                   const u16* __restrict__ kg,
                                                   const u16* __restrict__ vTg,
                                                   u16* __restrict__ og) {
  const int bid = blockIdx.x;
  const int wg = (bid & 7) * 64 + (bid >> 3);   // bijective XCD swizzle (512 = 8*64)
  const int qt = wg & 31, h = wg >> 5;
  const int tid = threadIdx.x, w = tid >> 6, l = tid & 63;
  const int g = w & 1, kq = w >> 1;
  const int q31 = l & 31, hi = l >> 5;
  const int hi16 = hi * 16, hi4 = hi * 4;

  __shared__ __align__(16) char smem[65536];

  auto stage = [&](int it, int b_) {
    #pragma unroll
    for (int c = 0; c < 4; ++c) {
      const int j = tid + c * 512;             // 0..2047 -> 32KB
      const int s_ = j >> 9;                   // stream = key-quarter
      const int rem = j & 511;
      const int isV = rem >> 8;
      const int cc = rem & 255;
      const char* src;
      if (isV) {
        const int r = cc >> 2, c16 = cc & 3;   // V^T tile [64 d][32 keys = 64B]
        const int colb = (c16 * 16) ^ (((r >> 2) & 3) << 4);
        src = (const char*)vTg + (size_t)(h * HD + r) * 4096 + s_ * 1024 + it * 64 + colb;
      } else {
        const int r = cc >> 3, c16 = cc & 7;   // K tile [32 keys][128B]
        const int colb = (c16 * 16) ^ ((r & 7) << 4);
        src = (const char*)kg + (size_t)(s_ * 512 + it * 32 + r) * 2048 + h * 128 + colb;
      }
      g2l16(src, &smem[s_ * 16384 + b_ * 8192 + isV * 4096 + cc * 16]);
    }
  };

  // Q fragments (B-operand): lane q-col = q31
  const char* qrow = (const char*)qg + (size_t)(qt * 64 + g * 32 + q31) * 2048 + h * 128;
  short8v qf[4];
  #pragma unroll
  for (int t = 0; t < 4; ++t) qf[t] = *(const short8v*)(qrow + t * 32 + hi16);

  stage(0, 0);
  __syncthreads();

  float m_s = -1e30f, l_s = 0.f;
  f32x16 accO[2];
  #pragma unroll
  for (int ds = 0; ds < 2; ++ds)
    #pragma unroll
    for (int r = 0; r < 16; ++r) accO[ds][r] = 0.f;

  const int kswz = (q31 & 7) << 4;            // K row swizzle key (row = q31)
  const int vswz = ((q31 >> 2) & 3) << 4;     // V row swizzle key (row = ds*32+q31)

  for (int it = 0; it < 16; ++it) {
    const int b_ = it & 1;
    if (it < 15) stage(it + 1, b_ ^ 1);
    const int Kb = kq * 16384 + b_ * 8192;
    const int Vb = Kb + 4096;

    // S^T = K Q^T : lane holds S[key=(r&3)+8(r>>2)+4hi][q=q31] (exp2 domain)
    short8v kf[4];
    #pragma unroll
    for (int t = 0; t < 4; ++t)
      kf[t] = *(const short8v*)&smem[Kb + q31 * 128 + ((t * 32 + hi16) ^ kswz)];
    f32x16 s_;
    #pragma unroll
    for (int r = 0; r < 16; ++r) s_[r] = 0.f;
    __builtin_amdgcn_s_setprio(1);
    s_ = MFMA32(kf[0], qf[0], s_, 0, 0, 0);
    s_ = MFMA32(kf[1], qf[1], s_, 0, 0, 0);
    s_ = MFMA32(kf[2], qf[2], s_, 0, 0, 0);
    s_ = MFMA32(kf[3], qf[3], s_, 0, 0, 0);
    __builtin_amdgcn_s_setprio(0);

    // tile max over lane's 16 + partner half (same q)
    float a0 = fmaxf(fmaxf(s_[0], s_[1]), fmaxf(s_[2], s_[3]));
    float a1 = fmaxf(fmaxf(s_[4], s_[5]), fmaxf(s_[6], s_[7]));
    float a2 = fmaxf(fmaxf(s_[8], s_[9]), fmaxf(s_[10], s_[11]));
    float a3 = fmaxf(fmaxf(s_[12], s_[13]), fmaxf(s_[14], s_[15]));
    float tmax = fmaxf(fmaxf(a0, a1), fmaxf(a2, a3));
    tmax = fmaxf(tmax, __shfl_xor(tmax, 32, 64));

    if (!__all(tmax <= m_s + 11.0f)) {        // defer-max (T13)
      const float mn = fmaxf(m_s, tmax);
      const float al = __builtin_amdgcn_exp2f(m_s - mn);
      m_s = mn;
      l_s *= al;
      #pragma unroll
      for (int r = 0; r < 16; ++r) {
        const float ar = __shfl(al, (r & 3) + 8 * (r >> 2) + hi4, 64);
        accO[0][r] *= ar;
        accO[1][r] *= ar;
      }
    }

    // P = exp2(S - m); pack to bf16 A-frags in registers (T12)
    float p[16];
    #pragma unroll
    for (int r = 0; r < 16; ++r) p[r] = __builtin_amdgcn_exp2f(s_[r] - m_s);
    float rs = ((p[0] + p[1]) + (p[2] + p[3])) + ((p[4] + p[5]) + (p[6] + p[7])) +
               (((p[8] + p[9]) + (p[10] + p[11])) + ((p[12] + p[13]) + (p[14] + p[15])));
    rs += __shfl_xor(rs, 32, 64);
    l_s += rs;

    u32 c0, c1, c2, c3, c4, c5, c6, c7;
    asm("v_cvt_pk_bf16_f32 %0, %1, %2" : "=v"(c0) : "v"(p[0]), "v"(p[1]));
    asm("v_cvt_pk_bf16_f32 %0, %1, %2" : "=v"(c1) : "v"(p[2]), "v"(p[3]));
    asm("v_cvt_pk_bf16_f32 %0, %1, %2" : "=v"(c2) : "v"(p[4]), "v"(p[5]));
    asm("v_cvt_pk_bf16_f32 %0, %1, %2" : "=v"(c3) : "v"(p[6]), "v"(p[7]));
    asm("v_cvt_pk_bf16_f32 %0, %1, %2" : "=v"(c4) : "v"(p[8]), "v"(p[9]));
    asm("v_cvt_pk_bf16_f32 %0, %1, %2" : "=v"(c5) : "v"(p[10]), "v"(p[11]));
    asm("v_cvt_pk_bf16_f32 %0, %1, %2" : "=v"(c6) : "v"(p[12]), "v"(p[13]));
    asm("v_cvt_pk_bf16_f32 %0, %1, %2" : "=v"(c7) : "v"(p[14]), "v"(p[15]));
    asm volatile("v_permlane32_swap_b32 %0, %1" : "+v"(c0), "+v"(c2));
    asm volatile("v_permlane32_swap_b32 %0, %1" : "+v"(c1), "+v"(c3));
    asm volatile("v_permlane32_swap_b32 %0, %1" : "+v"(c4), "+v"(c6));
    asm volatile("v_permlane32_swap_b32 %0, %1" : "+v"(c5), "+v"(c7));
    union { u32 u[4]; short8v s; } pa0, pa1;
    pa0.u[0] = c0; pa0.u[1] = c1; pa0.u[2] = c2; pa0.u[3] = c3;
    pa1.u[0] = c4; pa1.u[1] = c5; pa1.u[2] = c6; pa1.u[3] = c7;

    // O += P V : B-frags from V^T tile rows ds*32+q31
    #pragma unroll
    for (int kst = 0; kst < 2; ++kst) {
      const short8v pa = kst ? pa1.s : pa0.s;
      short8v vb0 = *(const short8v*)&smem[Vb + q31 * 64 + ((kst * 32 + hi16) ^ vswz)];
      short8v vb1 = *(const short8v*)&smem[Vb + (32 + q31) * 64 + ((kst * 32 + hi16) ^ vswz)];
      __builtin_amdgcn_s_setprio(1);
      accO[0] = MFMA32(pa, vb0, accO[0], 0, 0, 0);
      accO[1] = MFMA32(pa, vb1, accO[1], 0, 0, 0);
      __builtin_amdgcn_s_setprio(0);
    }
    __syncthreads();
  }

  // ---- 4-way split-K merge in LDS (streams dead after final barrier) ----
  float* mm = (float*)&smem[32768];            // m[g][kq][32], l at +256 floats
  if (l < 32) {
    mm[(g * 4 + kq) * 32 + l] = m_s;
    mm[256 + (g * 4 + kq) * 32 + l] = l_s;
  }
  __syncthreads();
  float M = mm[(g * 4 + 0) * 32 + q31];
  M = fmaxf(M, mm[(g * 4 + 1) * 32 + q31]);
  M = fmaxf(M, mm[(g * 4 + 2) * 32 + q31]);
  M = fmaxf(M, mm[(g * 4 + 3) * 32 + q31]);
  float L = 0.f;
  #pragma unroll
  for (int j = 0; j < 4; ++j)
    L += mm[256 + (g * 4 + j) * 32 + q31] *
         __builtin_amdgcn_exp2f(mm[(g * 4 + j) * 32 + q31] - M);
  const float aown = __builtin_amdgcn_exp2f(m_s - M);
  const float linv = 1.f / L;

  float* obuf = (float*)&smem[g * 8192];       // [32 q][64 d] f32 per qgroup
  #pragma unroll
  for (int round = 3; round >= 0; --round) {
    if (kq == round) {
      #pragma unroll
      for (int r = 0; r < 16; ++r) {
        const int qr = (r & 3) + 8 * (r >> 2) + hi4;
        const float ar = __shfl(aown, qr, 64);
        float* p0 = &obuf[qr * 64 + q31];
        float* p1 = &obuf[qr * 64 + 32 + q31];
        if (round == 3) {
          *p0 = accO[0][r] * ar;
          *p1 = accO[1][r] * ar;
        } else if (round > 0) {
          *p0 += accO[0][r] * ar;
          *p1 += accO[1][r] * ar;
        } else {
          const float li = __shfl(linv, qr, 64);
          const int row = qt * 64 + g * 32 + qr;
          og[(size_t)row * DIM + h * HD + q31] = f2b((accO[0][r] * ar + *p0) * li);
          og[(size_t)row * DIM + h * HD + 32 + q31] = f2b((accO[1][r] * ar + *p1) * li);
        }
      }
    }
    __syncthreads();
  }
}

// ---------- LayerNorm + per-modality affine + scatter (sums split-K partials) ----------
__global__ __launch_bounds__(256) void ln_scatter(const float* __restrict__ oa,
                                                  const float* __restrict__ ob,
                                                  const float* __restrict__ lnw,
                                                  const float* __restrict__ lnb,
                                                  const int* __restrict__ perm,
                                                  const int* __restrict__ cntp,
                                                  float* __restrict__ out) {
  const int i = blockIdx.x;
  const int tid = threadIdx.x, w = tid >> 6, l = tid & 63;
  const int mod = (i < cntp[0]) ? 0 : 1;
  float4 va = ((const float4*)(oa + (size_t)i * DIM))[tid];
  float4 vb = ((const float4*)(ob + (size_t)i * DIM))[tid];
  float4 v;
  v.x = va.x + vb.x; v.y = va.y + vb.y; v.z = va.z + vb.z; v.w = va.w + vb.w;
  float s = v.x + v.y + v.z + v.w;
  float ss = v.x * v.x + v.y * v.y + v.z * v.z + v.w * v.w;
  #pragma unroll
  for (int off = 1; off < 64; off <<= 1) {
    s += __shfl_xor(s, off, 64);
    ss += __shfl_xor(ss, off, 64);
  }
  __shared__ float rs4[4], rss4[4];
  if (l == 0) { rs4[w] = s; rss4[w] = ss; }
  __syncthreads();
  const float st = rs4[0] + rs4[1] + rs4[2] + rs4[3];
  const float sst = rss4[0] + rss4[1] + rss4[2] + rss4[3];
  const float mu = st * (1.f / DIM);
  const float var = sst * (1.f / DIM) - mu * mu;
  const float rstd = rsqrtf(var + 1e-5f);
  const int drow = perm[i];
  float4 g = ((const float4*)(lnw + (size_t)mod * DIM))[tid];
  float4 b = ((const float4*)(lnb + (size_t)mod * DIM))[tid];
  float4 rr;
  rr.x = (v.x - mu) * rstd * g.x + b.x;
  rr.y = (v.y - mu) * rstd * g.y + b.y;
  rr.z = (v.z - mu) * rstd * g.z + b.z;
  rr.w = (v.w - mu) * rstd * g.w + b.w;
  ((float4*)(out + (size_t)drow * DIM))[tid] = rr;
}

// ---------- launch ----------
extern "C" void kernel_launch(void* const* d_in, const int* in_sizes, int n_in,
                              void* d_out, int out_size, void* d_ws, size_t ws_size,
                              hipStream_t stream) {
  const float* x = (const float*)d_in[0];
  const void* masks = d_in[1];
  const float* wq = (const float*)d_in[3];
  const float* wk = (const float*)d_in[4];
  const float* wv = (const float*)d_in[5];
  const float* wo = (const float*)d_in[6];
  const float* lnw = (const float*)d_in[7];
  const float* lnb = (const float*)d_in[8];

  char* ws = (char*)d_ws;
  int* perm = (int*)(ws + OFF_PERM);
  int* cnt = (int*)(ws + OFF_CNT);
  u16* xpb = (u16*)(ws + OFF_XPB);
  u16* wT = (u16*)(ws + OFF_WT);
  u16* q = (u16*)(ws + OFF_Q);
  u16* k = (u16*)(ws + OFF_K);
  u16* v = (u16*)(ws + OFF_V);
  u16* vT = (u16*)(ws + OFF_VT);
  u16* at = (u16*)(ws + OFF_AT);
  float* o = (float*)(ws + OFF_O);
  float* o2 = (float*)(ws + OFF_O2);
  float* out = (float*)d_out;

  prep_kernel<<<1, 256, 0, stream>>>(masks, perm, cnt);
  gather_cast<<<N_TOK, 256, 0, stream>>>(x, perm, xpb);
  wcast<<<dim3(32, 32, 8), dim3(32, 8), 0, stream>>>(wq, wk, wv, wo, wT);
  gemm_exp<0><<<dim3(8, 32, 3), 256, 0, stream>>>(xpb, wT, 0, QSCALE, 0, q, k, v, cnt);
  vtrans<<<dim3(64, 2, 16), dim3(32, 8), 0, stream>>>(v, vT);
  attn_fwd<<<512, 512, 0, stream>>>(q, k, vT, at);
  gemm_exp<1><<<dim3(8, 32, 2), 256, 0, stream>>>(at, wT, 3, 1.0f, 1, o, o2, o, cnt);
  ln_scatter<<<N_TOK, 256, 0, stream>>>(o, o2, lnw, lnb, perm, cnt, out);
}

// Round 7
// 93.750 us; speedup vs baseline: 1.4876x; 1.1443x over previous
//
#include <hip/hip_runtime.h>

typedef __attribute__((ext_vector_type(8))) short short8v;
typedef __attribute__((ext_vector_type(4))) float f32x4;
typedef __attribute__((ext_vector_type(16))) float f32x16;
typedef unsigned short u16;
typedef unsigned int u32;

#define MFMA __builtin_amdgcn_mfma_f32_16x16x32_bf16
#define MFMA32 __builtin_amdgcn_mfma_f32_32x32x16_bf16

// ---------- helpers ----------
__device__ __forceinline__ u16 f2b(float f) {
  u32 u = __float_as_uint(f);
  u = (u + 0x7FFFu + ((u >> 16) & 1u)) >> 16;
  return (u16)u;
}
__device__ __forceinline__ void g2l16(const void* g, void* l) {
  __builtin_amdgcn_global_load_lds(
      (const __attribute__((address_space(1))) unsigned int*)g,
      (__attribute__((address_space(3))) unsigned int*)l, 16, 0, 0);
}

// sizes
#define N_TOK 2048
#define DIM 1024
#define NH 16
#define HD 64

// Q pre-scale: hd^-0.5 * log2(e)  (softmax runs in exp2 domain)
#define QSCALE 0.18033688011112042f

// workspace layout (bytes)
#define OFF_PERM 0
#define OFF_CNT 8192
#define OFF_XPB 16384
#define OFF_WT (OFF_XPB + 4194304)          // 16 MB: [tensor][expert][1024][1024] bf16, WT[n][k]
#define OFF_Q (OFF_WT + 16777216)
#define OFF_K (OFF_Q + 4194304)
#define OFF_V (OFF_K + 4194304)
#define OFF_VT (OFF_V + 4194304)            // [16][64][2048] bf16
#define OFF_AT (OFF_VT + 4194304)
#define OFF_O (OFF_AT + 4194304)            // f32 [2048][1024]
#define OFF_O2 (OFF_O + 8388608)            // f32 [2048][1024] split-K partial

// ---------- fused: weight transpose-cast (z<8) + prep partition (z==8) ----------
__global__ __launch_bounds__(256) void wcast_prep(const float* __restrict__ wq,
                                                  const float* __restrict__ wk,
                                                  const float* __restrict__ wv,
                                                  const float* __restrict__ wo,
                                                  u16* __restrict__ wT,
                                                  const void* __restrict__ masks,
                                                  int* __restrict__ perm,
                                                  int* __restrict__ cnt) {
  __shared__ float t[32][33];
  __shared__ u32 red[256];
  __shared__ int scan[256];
  const int tx = threadIdx.x, ty = threadIdx.y;
  if (blockIdx.z == 8) {
    if (blockIdx.x != 0 || blockIdx.y != 0) return;
    const int tid = ty * 32 + tx;
    const u32* mw = (const u32*)masks;
    u32 mx = 0;
    for (int i = tid; i < 1024; i += 256) { u32 v = mw[i]; mx = mx > v ? mx : v; }
    red[tid] = mx;
    __syncthreads();
    for (int off = 128; off; off >>= 1) {
      if (tid < off) red[tid] = red[tid] > red[tid + off] ? red[tid] : red[tid + off];
      __syncthreads();
    }
    const bool isbyte = red[0] > 1u;
    int md[8];
    int c0loc = 0;
    #pragma unroll
    for (int j = 0; j < 8; ++j) {
      const int n = tid * 8 + j;
      int m1;
      if (isbyte) m1 = ((const unsigned char*)masks)[N_TOK + n] != 0;
      else        m1 = mw[N_TOK + n] != 0;
      md[j] = m1;
      c0loc += (m1 == 0);
    }
    scan[tid] = c0loc;
    __syncthreads();
    for (int off = 1; off < 256; off <<= 1) {
      int v = (tid >= off) ? scan[tid - off] : 0;
      __syncthreads();
      scan[tid] += v;
      __syncthreads();
    }
    const int incl = scan[tid];
    const int total0 = scan[255];
    const int excl0 = incl - c0loc;
    int p0 = excl0;
    int p1 = total0 + (tid * 8 - excl0);
    #pragma unroll
    for (int j = 0; j < 8; ++j) {
      const int n = tid * 8 + j;
      if (!md[j]) perm[p0++] = n; else perm[p1++] = n;
    }
    if (tid == 0) cnt[0] = total0;
    return;
  }
  const int mat = blockIdx.z;               // tensor*2 + expert
  const int tensor = mat >> 1, expert = mat & 1;
  const float* src = (tensor == 0) ? wq : (tensor == 1) ? wk : (tensor == 2) ? wv : wo;
  src += (size_t)expert * (1 << 20);
  u16* dst = wT + ((size_t)mat << 20);
  const int k0 = blockIdx.x * 32, n0 = blockIdx.y * 32;
  #pragma unroll
  for (int r = 0; r < 4; ++r)
    t[ty + 8 * r][tx] = src[(size_t)(k0 + ty + 8 * r) * DIM + n0 + tx];
  __syncthreads();
  #pragma unroll
  for (int r = 0; r < 4; ++r)
    dst[(size_t)(n0 + ty + 8 * r) * DIM + k0 + tx] = f2b(t[tx][ty + 8 * r]);
}

// ---------- gather + cast x -> xp bf16 ----------
__global__ __launch_bounds__(256) void gather_cast(const float* __restrict__ x,
                                                   const int* __restrict__ perm,
                                                   u16* __restrict__ xpb) {
  const int i = blockIdx.x;
  const int src = perm[i];
  const int tid = threadIdx.x;
  float4 v = ((const float4*)(x + (size_t)src * DIM))[tid];
  ushort4 o;
  o.x = f2b(v.x); o.y = f2b(v.y); o.z = f2b(v.z); o.w = f2b(v.w);
  ((ushort4*)(xpb + (size_t)i * DIM))[tid] = o;
}

// ---------- V transpose per head: v[n][h*64+d] -> vT[h][d][n] ----------
__global__ __launch_bounds__(256) void vtrans(const u16* __restrict__ v,
                                              u16* __restrict__ vT) {
  const int h = blockIdx.z;
  const int n0 = blockIdx.x * 32, d0 = blockIdx.y * 32;
  const int tx = threadIdx.x, ty = threadIdx.y;
  __shared__ u16 t[32][33];
  #pragma unroll
  for (int r = 0; r < 4; ++r)
    t[ty + 8 * r][tx] = v[(size_t)(n0 + ty + 8 * r) * DIM + h * HD + d0 + tx];
  __syncthreads();
  #pragma unroll
  for (int r = 0; r < 4; ++r)
    vT[(size_t)(h * HD + d0 + ty + 8 * r) * N_TOK + n0 + tx] = t[tx][ty + 8 * r];
}

// ---------- expert GEMM: BK=64, T2 swizzled LDS, optional split-K ----------
template <int OUTF32>
__global__ __launch_bounds__(256) void gemm_exp(const u16* __restrict__ X,
                                                const u16* __restrict__ WTall,
                                                int tensor0, float scale0,
                                                int split_k,
                                                void* __restrict__ o0,
                                                void* __restrict__ o1,
                                                void* __restrict__ o2,
                                                const int* __restrict__ cntp) {
  const int z = blockIdx.z;
  const int e = blockIdx.y >> 4;
  const int mt = blockIdx.y & 15;
  const int c0 = cntp[0];
  const int lo = e ? c0 : 0;
  const int hi = e ? N_TOK : c0;
  const int rb = mt * 128;
  if (rb >= hi || rb + 128 <= lo) return;
  const int cb = blockIdx.x * 128;
  int tensor, kstart, kiters;
  void* OUT;
  float scl;
  if (split_k) {            // z = K-half (of 16 BK64 steps)
    tensor = tensor0; OUT = z ? o1 : o0; kstart = z * 8; kiters = 8; scl = 1.f;
  } else {                  // z = tensor index
    tensor = tensor0 + z; OUT = (z == 0) ? o0 : (z == 1) ? o1 : o2;
    kstart = 0; kiters = 16; scl = (z == 0) ? scale0 : 1.f;
  }
  const u16* W = WTall + ((size_t)(tensor * 2 + e) << 20);

  const int tid = threadIdx.x;
  const int w = tid >> 6, l = tid & 63, lg = l >> 4, ln = l & 15;
  const int wm = (w >> 1) * 64, wn = (w & 1) * 64;

  __shared__ __align__(16) char smem[65536];   // 2 bufs x (A 16K + B 16K)

  auto stage = [&](int it, int b_) {
    #pragma unroll
    for (int c = 0; c < 8; ++c) {
      const int j = tid + c * 256;             // 0..2047
      const int isB = j >> 10;
      const int cc = j & 1023;
      const int row = cc >> 3;
      const int colb = ((cc & 7) * 16) ^ ((row & 7) << 4);  // pre-swizzled source
      const char* base = isB ? (const char*)W + (size_t)(cb + row) * 2048
                             : (const char*)X + (size_t)(rb + row) * 2048;
      g2l16(base + it * 128 + colb, &smem[b_ * 32768 + isB * 16384 + cc * 16]);
    }
  };

  f32x4 acc[4][4];
  #pragma unroll
  for (int i = 0; i < 4; ++i)
    #pragma unroll
    for (int j = 0; j < 4; ++j) acc[i][j] = (f32x4){0.f, 0.f, 0.f, 0.f};

  const int aswz = (ln & 7) << 4;
  stage(kstart, 0);
  __syncthreads();
  for (int ii = 0; ii < kiters; ++ii) {
    const int b_ = ii & 1;
    if (ii < kiters - 1) stage(kstart + ii + 1, b_ ^ 1);
    #pragma unroll
    for (int ks = 0; ks < 2; ++ks) {
      short8v a[4], bb[4];
      #pragma unroll
      for (int mi = 0; mi < 4; ++mi)
        a[mi] = *(const short8v*)&smem[b_ * 32768 + (wm + mi * 16 + ln) * 128 +
                                       ((ks * 64 + lg * 16) ^ aswz)];
      #pragma unroll
      for (int ni = 0; ni < 4; ++ni)
        bb[ni] = *(const short8v*)&smem[b_ * 32768 + 16384 + (wn + ni * 16 + ln) * 128 +
                                        ((ks * 64 + lg * 16) ^ aswz)];
      __builtin_amdgcn_s_setprio(1);
      #pragma unroll
      for (int mi = 0; mi < 4; ++mi)
        #pragma unroll
        for (int ni = 0; ni < 4; ++ni)
          acc[mi][ni] = MFMA(a[mi], bb[ni], acc[mi][ni], 0, 0, 0);
      __builtin_amdgcn_s_setprio(0);
    }
    __syncthreads();
  }

  #pragma unroll
  for (int mi = 0; mi < 4; ++mi) {
    #pragma unroll
    for (int r = 0; r < 4; ++r) {
      const int row = rb + wm + mi * 16 + lg * 4 + r;
      if (row >= lo && row < hi) {
        #pragma unroll
        for (int ni = 0; ni < 4; ++ni) {
          const int col = cb + wn + ni * 16 + ln;
          const float vv = acc[mi][ni][r] * scl;
          if (OUTF32) ((float*)OUT)[(size_t)row * DIM + col] = vv;
          else ((u16*)OUT)[(size_t)row * DIM + col] = f2b(vv);
        }
      }
    }
  }
}

// ---------- flash attention: barrier-free, wave-private K/V streams ----------
// grid: 512 blocks (32 qtiles x 16 heads, XCD-swizzled); block = 4 waves.
// Wave w = key-quarter kq: 64 q rows (2 B-frag sets) x 512 keys (16 iters of 32).
// Private 8KB LDS slice per wave (K 4KB + V 4KB, single-buffered, T14 reg-staged:
// loads issued one iter ahead, ds_write placed after the reads it must follow).
// No __syncthreads in the main loop; 4-way split-K merge at the end.
__global__ __launch_bounds__(256, 2) void attn_fwd(const u16* __restrict__ qg,
                                                   const u16* __restrict__ kg,
                                                   const u16* __restrict__ vTg,
                                                   u16* __restrict__ og) {
  const int bid = blockIdx.x;
  const int wg = (bid & 7) * 64 + (bid >> 3);   // bijective XCD swizzle (512 = 8*64)
  const int qt = wg & 31, h = wg >> 5;
  const int tid = threadIdx.x, kq = tid >> 6, l = tid & 63;
  const int q31 = l & 31, hi = l >> 5;
  const int hi16 = hi * 16, hi4 = hi * 4;

  __shared__ __align__(16) char smem[34816];   // 4 waves x 8KB + 2KB merge m/l
  const int Kb = kq * 8192, Vb = Kb + 4096;

  // per-lane staging source bases (inverse-swizzled so LDS writes are linear)
  const int lr3 = l >> 3, lc3 = l & 7;
  const char* baseK = (const char*)kg + (size_t)(kq * 512 + lr3) * 2048 + h * 128 +
                      ((lc3 << 4) ^ (lr3 << 4));
  const int cpr = lc3 ^ lr3;                  // swizzled col/16 for V (and K)
  const int dhalf = (cpr >> 2) & 1;
  const char* baseV = (const char*)vTg + (size_t)(h * 64 + lr3 + dhalf * 32) * 4096 +
                      kq * 1024 + ((cpr & 3) << 4);

  // Q fragments (B-operand), 2 sets of 32 q-cols
  const char* qb0 = (const char*)qg + (size_t)(qt * 64 + q31) * 2048 + h * 128;
  short8v qfA[4], qfB[4];
  #pragma unroll
  for (int t = 0; t < 4; ++t) {
    qfA[t] = *(const short8v*)(qb0 + t * 32 + hi16);
    qfB[t] = *(const short8v*)(qb0 + 65536 + t * 32 + hi16);
  }

  uint4 rk0, rk1, rk2, rk3, rv0, rv1, rv2, rv3;
  auto loadKV = [&](int it) {
    const char* pk = baseK + (size_t)it * 65536;   // 32 key-rows x 2048B
    rk0 = *(const uint4*)(pk);
    rk1 = *(const uint4*)(pk + 16384);
    rk2 = *(const uint4*)(pk + 32768);
    rk3 = *(const uint4*)(pk + 49152);
    const char* pv = baseV + it * 64;              // 32 keys x 2B
    rv0 = *(const uint4*)(pv);
    rv1 = *(const uint4*)(pv + 32768);
    rv2 = *(const uint4*)(pv + 65536);
    rv3 = *(const uint4*)(pv + 98304);
  };
  auto writeK = [&]() {
    *(uint4*)&smem[Kb + 0 + l * 16] = rk0;
    *(uint4*)&smem[Kb + 1024 + l * 16] = rk1;
    *(uint4*)&smem[Kb + 2048 + l * 16] = rk2;
    *(uint4*)&smem[Kb + 3072 + l * 16] = rk3;
  };
  auto writeV = [&]() {
    *(uint4*)&smem[Vb + 0 + l * 16] = rv0;
    *(uint4*)&smem[Vb + 1024 + l * 16] = rv1;
    *(uint4*)&smem[Vb + 2048 + l * 16] = rv2;
    *(uint4*)&smem[Vb + 3072 + l * 16] = rv3;
  };

  float mA = -1e30f, lA = 0.f, mB = -1e30f, lB = 0.f;
  f32x16 accA0, accA1, accB0, accB1;
  #pragma unroll
  for (int r = 0; r < 16; ++r) { accA0[r] = 0.f; accA1[r] = 0.f; accB0[r] = 0.f; accB1[r] = 0.f; }

  struct PA { short8v p0, p1; };
  // softmax for one q-set: updates (m,l), rescales acc pair, returns P A-frags
  auto softmax = [&](f32x16& s_, float& m_s, float& l_s, f32x16& a0, f32x16& a1) -> PA {
    float t0 = fmaxf(fmaxf(s_[0], s_[1]), fmaxf(s_[2], s_[3]));
    float t1 = fmaxf(fmaxf(s_[4], s_[5]), fmaxf(s_[6], s_[7]));
    float t2 = fmaxf(fmaxf(s_[8], s_[9]), fmaxf(s_[10], s_[11]));
    float t3 = fmaxf(fmaxf(s_[12], s_[13]), fmaxf(s_[14], s_[15]));
    float tmax = fmaxf(fmaxf(t0, t1), fmaxf(t2, t3));
    tmax = fmaxf(tmax, __shfl_xor(tmax, 32, 64));
    if (!__all(tmax <= m_s + 11.0f)) {        // defer-max (T13)
      const float mn = fmaxf(m_s, tmax);
      const float al = __builtin_amdgcn_exp2f(m_s - mn);
      m_s = mn;
      l_s *= al;
      #pragma unroll
      for (int r = 0; r < 16; ++r) {
        const float ar = __shfl(al, (r & 3) + 8 * (r >> 2) + hi4, 64);
        a0[r] *= ar;
        a1[r] *= ar;
      }
    }
    float p[16];
    #pragma unroll
    for (int r = 0; r < 16; ++r) p[r] = __builtin_amdgcn_exp2f(s_[r] - m_s);
    float rs = ((p[0] + p[1]) + (p[2] + p[3])) + ((p[4] + p[5]) + (p[6] + p[7])) +
               (((p[8] + p[9]) + (p[10] + p[11])) + ((p[12] + p[13]) + (p[14] + p[15])));
    rs += __shfl_xor(rs, 32, 64);
    l_s += rs;
    u32 c0, c1, c2, c3, c4, c5, c6, c7;
    asm("v_cvt_pk_bf16_f32 %0, %1, %2" : "=v"(c0) : "v"(p[0]), "v"(p[1]));
    asm("v_cvt_pk_bf16_f32 %0, %1, %2" : "=v"(c1) : "v"(p[2]), "v"(p[3]));
    asm("v_cvt_pk_bf16_f32 %0, %1, %2" : "=v"(c2) : "v"(p[4]), "v"(p[5]));
    asm("v_cvt_pk_bf16_f32 %0, %1, %2" : "=v"(c3) : "v"(p[6]), "v"(p[7]));
    asm("v_cvt_pk_bf16_f32 %0, %1, %2" : "=v"(c4) : "v"(p[8]), "v"(p[9]));
    asm("v_cvt_pk_bf16_f32 %0, %1, %2" : "=v"(c5) : "v"(p[10]), "v"(p[11]));
    asm("v_cvt_pk_bf16_f32 %0, %1, %2" : "=v"(c6) : "v"(p[12]), "v"(p[13]));
    asm("v_cvt_pk_bf16_f32 %0, %1, %2" : "=v"(c7) : "v"(p[14]), "v"(p[15]));
    asm volatile("v_permlane32_swap_b32 %0, %1" : "+v"(c0), "+v"(c2));
    asm volatile("v_permlane32_swap_b32 %0, %1" : "+v"(c1), "+v"(c3));
    asm volatile("v_permlane32_swap_b32 %0, %1" : "+v"(c4), "+v"(c6));
    asm volatile("v_permlane32_swap_b32 %0, %1" : "+v"(c5), "+v"(c7));
    union { u32 u[4]; short8v s; } u0, u1;
    u0.u[0] = c0; u0.u[1] = c1; u0.u[2] = c2; u0.u[3] = c3;
    u1.u[0] = c4; u1.u[1] = c5; u1.u[2] = c6; u1.u[3] = c7;
    PA out;
    out.p0 = u0.s;
    out.p1 = u1.s;
    return out;
  };

  const int kswz = (q31 & 7) << 4;
  loadKV(0);
  writeK();
  writeV();

  #pragma unroll 1
  for (int it = 0; it < 16; ++it) {
    if (it < 15) loadKV(it + 1);
    // K frags (lane = key row q31)
    short8v kf0 = *(const short8v*)&smem[Kb + q31 * 128 + ((0 + hi16) ^ kswz)];
    short8v kf1 = *(const short8v*)&smem[Kb + q31 * 128 + ((32 + hi16) ^ kswz)];
    short8v kf2 = *(const short8v*)&smem[Kb + q31 * 128 + ((64 + hi16) ^ kswz)];
    short8v kf3 = *(const short8v*)&smem[Kb + q31 * 128 + ((96 + hi16) ^ kswz)];
    f32x16 sA, sB;
    #pragma unroll
    for (int r = 0; r < 16; ++r) { sA[r] = 0.f; sB[r] = 0.f; }
    __builtin_amdgcn_s_setprio(1);
    sA = MFMA32(kf0, qfA[0], sA, 0, 0, 0);
    sB = MFMA32(kf0, qfB[0], sB, 0, 0, 0);
    sA = MFMA32(kf1, qfA[1], sA, 0, 0, 0);
    sB = MFMA32(kf1, qfB[1], sB, 0, 0, 0);
    sA = MFMA32(kf2, qfA[2], sA, 0, 0, 0);
    sB = MFMA32(kf2, qfB[2], sB, 0, 0, 0);
    sA = MFMA32(kf3, qfA[3], sA, 0, 0, 0);
    sB = MFMA32(kf3, qfB[3], sB, 0, 0, 0);
    __builtin_amdgcn_s_setprio(0);
    if (it < 15) writeK();                    // waits vmcnt(RK); K reads already done

    PA pA = softmax(sA, mA, lA, accA0, accA1);
    PA pB = softmax(sB, mB, lB, accB0, accB1);

    // V frags: row = q31 (d), col = ds*64 + kk*32 + hi16 (paired-d 128B rows)
    short8v vf00 = *(const short8v*)&smem[Vb + q31 * 128 + ((0 + hi16) ^ kswz)];
    short8v vf01 = *(const short8v*)&smem[Vb + q31 * 128 + ((64 + hi16) ^ kswz)];
    short8v vf10 = *(const short8v*)&smem[Vb + q31 * 128 + ((32 + hi16) ^ kswz)];
    short8v vf11 = *(const short8v*)&smem[Vb + q31 * 128 + ((96 + hi16) ^ kswz)];
    __builtin_amdgcn_s_setprio(1);
    accA0 = MFMA32(pA.p0, vf00, accA0, 0, 0, 0);
    accA1 = MFMA32(pA.p0, vf01, accA1, 0, 0, 0);
    accB0 = MFMA32(pB.p0, vf00, accB0, 0, 0, 0);
    accB1 = MFMA32(pB.p0, vf01, accB1, 0, 0, 0);
    accA0 = MFMA32(pA.p1, vf10, accA0, 0, 0, 0);
    accA1 = MFMA32(pA.p1, vf11, accA1, 0, 0, 0);
    accB0 = MFMA32(pB.p1, vf10, accB0, 0, 0, 0);
    accB1 = MFMA32(pB.p1, vf11, accB1, 0, 0, 0);
    __builtin_amdgcn_s_setprio(0);
    if (it < 15) writeV();                    // V reads done; waits vmcnt(RV)
  }
  __syncthreads();

  // ---- 4-way split-K merge (staging LDS dead; reuse) ----
  float* mm = (float*)&smem[32768];           // m[set][kq][32], l at +256 floats
  if (l < 32) {
    mm[(0 * 4 + kq) * 32 + l] = mA;
    mm[(1 * 4 + kq) * 32 + l] = mB;
    mm[256 + (0 * 4 + kq) * 32 + l] = lA;
    mm[256 + (1 * 4 + kq) * 32 + l] = lB;
  }
  __syncthreads();
  float MA = mm[0 * 32 + q31], MB = mm[4 * 32 + q31];
  #pragma unroll
  for (int j = 1; j < 4; ++j) {
    MA = fmaxf(MA, mm[(0 * 4 + j) * 32 + q31]);
    MB = fmaxf(MB, mm[(1 * 4 + j) * 32 + q31]);
  }
  float LA = 0.f, LB = 0.f;
  #pragma unroll
  for (int j = 0; j < 4; ++j) {
    LA += mm[256 + (0 * 4 + j) * 32 + q31] * __builtin_amdgcn_exp2f(mm[(0 * 4 + j) * 32 + q31] - MA);
    LB += mm[256 + (1 * 4 + j) * 32 + q31] * __builtin_amdgcn_exp2f(mm[(1 * 4 + j) * 32 + q31] - MB);
  }
  const float aA = __builtin_amdgcn_exp2f(mA - MA), liA = 1.f / LA;
  const float aB = __builtin_amdgcn_exp2f(mB - MB), liB = 1.f / LB;

  float* obuf = (float*)&smem[0];             // [64 q][64 d] f32
  #pragma unroll
  for (int round = 3; round >= 0; --round) {
    if (kq == round) {
      #pragma unroll
      for (int r = 0; r < 16; ++r) {
        const int qr = (r & 3) + 8 * (r >> 2) + hi4;
        const float arA = __shfl(aA, qr, 64);
        const float arB = __shfl(aB, qr, 64);
        float* pa0 = &obuf[qr * 64 + q31];
        float* pa1 = &obuf[qr * 64 + 32 + q31];
        float* pb0 = &obuf[(32 + qr) * 64 + q31];
        float* pb1 = &obuf[(32 + qr) * 64 + 32 + q31];
        if (round == 3) {
          *pa0 = accA0[r] * arA; *pa1 = accA1[r] * arA;
          *pb0 = accB0[r] * arB; *pb1 = accB1[r] * arB;
        } else if (round > 0) {
          *pa0 += accA0[r] * arA; *pa1 += accA1[r] * arA;
          *pb0 += accB0[r] * arB; *pb1 += accB1[r] * arB;
        } else {
          const float lrA = __shfl(liA, qr, 64);
          const float lrB = __shfl(liB, qr, 64);
          const int rowA = qt * 64 + qr, rowB = qt * 64 + 32 + qr;
          og[(size_t)rowA * DIM + h * HD + q31] = f2b((accA0[r] * arA + *pa0) * lrA);
          og[(size_t)rowA * DIM + h * HD + 32 + q31] = f2b((accA1[r] * arA + *pa1) * lrA);
          og[(size_t)rowB * DIM + h * HD + q31] = f2b((accB0[r] * arB + *pb0) * lrB);
          og[(size_t)rowB * DIM + h * HD + 32 + q31] = f2b((accB1[r] * arB + *pb1) * lrB);
        }
      }
    }
    __syncthreads();
  }
}

// ---------- LayerNorm + per-modality affine + scatter (sums split-K partials) ----------
__global__ __launch_bounds__(256) void ln_scatter(const float* __restrict__ oa,
                                                  const float* __restrict__ ob,
                                                  const float* __restrict__ lnw,
                                                  const float* __restrict__ lnb,
                                                  const int* __restrict__ perm,
                                                  const int* __restrict__ cntp,
                                                  float* __restrict__ out) {
  const int i = blockIdx.x;
  const int tid = threadIdx.x, w = tid >> 6, l = tid & 63;
  const int mod = (i < cntp[0]) ? 0 : 1;
  float4 va = ((const float4*)(oa + (size_t)i * DIM))[tid];
  float4 vb = ((const float4*)(ob + (size_t)i * DIM))[tid];
  float4 v;
  v.x = va.x + vb.x; v.y = va.y + vb.y; v.z = va.z + vb.z; v.w = va.w + vb.w;
  float s = v.x + v.y + v.z + v.w;
  float ss = v.x * v.x + v.y * v.y + v.z * v.z + v.w * v.w;
  #pragma unroll
  for (int off = 1; off < 64; off <<= 1) {
    s += __shfl_xor(s, off, 64);
    ss += __shfl_xor(ss, off, 64);
  }
  __shared__ float rs4[4], rss4[4];
  if (l == 0) { rs4[w] = s; rss4[w] = ss; }
  __syncthreads();
  const float st = rs4[0] + rs4[1] + rs4[2] + rs4[3];
  const float sst = rss4[0] + rss4[1] + rss4[2] + rss4[3];
  const float mu = st * (1.f / DIM);
  const float var = sst * (1.f / DIM) - mu * mu;
  const float rstd = rsqrtf(var + 1e-5f);
  const int drow = perm[i];
  float4 g = ((const float4*)(lnw + (size_t)mod * DIM))[tid];
  float4 b = ((const float4*)(lnb + (size_t)mod * DIM))[tid];
  float4 rr;
  rr.x = (v.x - mu) * rstd * g.x + b.x;
  rr.y = (v.y - mu) * rstd * g.y + b.y;
  rr.z = (v.z - mu) * rstd * g.z + b.z;
  rr.w = (v.w - mu) * rstd * g.w + b.w;
  ((float4*)(out + (size_t)drow * DIM))[tid] = rr;
}

// ---------- launch ----------
extern "C" void kernel_launch(void* const* d_in, const int* in_sizes, int n_in,
                              void* d_out, int out_size, void* d_ws, size_t ws_size,
                              hipStream_t stream) {
  const float* x = (const float*)d_in[0];
  const void* masks = d_in[1];
  const float* wq = (const float*)d_in[3];
  const float* wk = (const float*)d_in[4];
  const float* wv = (const float*)d_in[5];
  const float* wo = (const float*)d_in[6];
  const float* lnw = (const float*)d_in[7];
  const float* lnb = (const float*)d_in[8];

  char* ws = (char*)d_ws;
  int* perm = (int*)(ws + OFF_PERM);
  int* cnt = (int*)(ws + OFF_CNT);
  u16* xpb = (u16*)(ws + OFF_XPB);
  u16* wT = (u16*)(ws + OFF_WT);
  u16* q = (u16*)(ws + OFF_Q);
  u16* k = (u16*)(ws + OFF_K);
  u16* v = (u16*)(ws + OFF_V);
  u16* vT = (u16*)(ws + OFF_VT);
  u16* at = (u16*)(ws + OFF_AT);
  float* o = (float*)(ws + OFF_O);
  float* o2 = (float*)(ws + OFF_O2);
  float* out = (float*)d_out;

  wcast_prep<<<dim3(32, 32, 9), dim3(32, 8), 0, stream>>>(wq, wk, wv, wo, wT, masks, perm, cnt);
  gather_cast<<<N_TOK, 256, 0, stream>>>(x, perm, xpb);
  gemm_exp<0><<<dim3(8, 32, 3), 256, 0, stream>>>(xpb, wT, 0, QSCALE, 0, q, k, v, cnt);
  vtrans<<<dim3(64, 2, 16), dim3(32, 8), 0, stream>>>(v, vT);
  attn_fwd<<<512, 256, 0, stream>>>(q, k, vT, at);
  gemm_exp<1><<<dim3(8, 32, 2), 256, 0, stream>>>(at, wT, 3, 1.0f, 1, o, o2, o, cnt);
  ln_scatter<<<N_TOK, 256, 0, stream>>>(o, o2, lnw, lnb, perm, cnt, out);
}

// Round 8
// 91.063 us; speedup vs baseline: 1.5316x; 1.0295x over previous
//
#include <hip/hip_runtime.h>

typedef __attribute__((ext_vector_type(8))) short short8v;
typedef __attribute__((ext_vector_type(4))) float f32x4;
typedef __attribute__((ext_vector_type(16))) float f32x16;
typedef unsigned short u16;
typedef unsigned int u32;

#define MFMA __builtin_amdgcn_mfma_f32_16x16x32_bf16
#define MFMA32 __builtin_amdgcn_mfma_f32_32x32x16_bf16

// ---------- helpers ----------
__device__ __forceinline__ u16 f2b(float f) {
  u32 u = __float_as_uint(f);
  u = (u + 0x7FFFu + ((u >> 16) & 1u)) >> 16;
  return (u16)u;
}
__device__ __forceinline__ void g2l16(const void* g, void* l) {
  __builtin_amdgcn_global_load_lds(
      (const __attribute__((address_space(1))) unsigned int*)g,
      (__attribute__((address_space(3))) unsigned int*)l, 16, 0, 0);
}

// sizes
#define N_TOK 2048
#define DIM 1024
#define NH 16
#define HD 64

// Q pre-scale: hd^-0.5 * log2(e)  (softmax runs in exp2 domain)
#define QSCALE 0.18033688011112042f

// workspace layout (bytes)
#define OFF_PERM 0
#define OFF_CNT 8192
#define OFF_XPB 16384
#define OFF_WT (OFF_XPB + 4194304)          // 16 MB: [tensor][expert][1024][1024] bf16, WT[n][k]
#define OFF_Q (OFF_WT + 16777216)
#define OFF_K (OFF_Q + 4194304)
#define OFF_VT (OFF_K + 4194304)            // [16][64][2048] bf16
#define OFF_AT (OFF_VT + 4194304)
#define OFF_O (OFF_AT + 4194304)            // f32 [2048][1024]
#define OFF_O2 (OFF_O + 8388608)            // f32 [2048][1024] split-K partial

// ---------- fused: weight transpose-cast (z<8) + prep partition (z==8) ----------
__global__ __launch_bounds__(256) void wcast_prep(const float* __restrict__ wq,
                                                  const float* __restrict__ wk,
                                                  const float* __restrict__ wv,
                                                  const float* __restrict__ wo,
                                                  u16* __restrict__ wT,
                                                  const void* __restrict__ masks,
                                                  int* __restrict__ perm,
                                                  int* __restrict__ cnt) {
  __shared__ float t[32][33];
  __shared__ u32 red[256];
  __shared__ int scan[256];
  const int tx = threadIdx.x, ty = threadIdx.y;
  if (blockIdx.z == 8) {
    if (blockIdx.x != 0 || blockIdx.y != 0) return;
    const int tid = ty * 32 + tx;
    const u32* mw = (const u32*)masks;
    u32 mx = 0;
    for (int i = tid; i < 1024; i += 256) { u32 v = mw[i]; mx = mx > v ? mx : v; }
    red[tid] = mx;
    __syncthreads();
    for (int off = 128; off; off >>= 1) {
      if (tid < off) red[tid] = red[tid] > red[tid + off] ? red[tid] : red[tid + off];
      __syncthreads();
    }
    const bool isbyte = red[0] > 1u;
    int md[8];
    int c0loc = 0;
    #pragma unroll
    for (int j = 0; j < 8; ++j) {
      const int n = tid * 8 + j;
      int m1;
      if (isbyte) m1 = ((const unsigned char*)masks)[N_TOK + n] != 0;
      else        m1 = mw[N_TOK + n] != 0;
      md[j] = m1;
      c0loc += (m1 == 0);
    }
    scan[tid] = c0loc;
    __syncthreads();
    for (int off = 1; off < 256; off <<= 1) {
      int v = (tid >= off) ? scan[tid - off] : 0;
      __syncthreads();
      scan[tid] += v;
      __syncthreads();
    }
    const int incl = scan[tid];
    const int total0 = scan[255];
    const int excl0 = incl - c0loc;
    int p0 = excl0;
    int p1 = total0 + (tid * 8 - excl0);
    #pragma unroll
    for (int j = 0; j < 8; ++j) {
      const int n = tid * 8 + j;
      if (!md[j]) perm[p0++] = n; else perm[p1++] = n;
    }
    if (tid == 0) cnt[0] = total0;
    return;
  }
  const int mat = blockIdx.z;               // tensor*2 + expert
  const int tensor = mat >> 1, expert = mat & 1;
  const float* src = (tensor == 0) ? wq : (tensor == 1) ? wk : (tensor == 2) ? wv : wo;
  src += (size_t)expert * (1 << 20);
  u16* dst = wT + ((size_t)mat << 20);
  const int k0 = blockIdx.x * 32, n0 = blockIdx.y * 32;
  #pragma unroll
  for (int r = 0; r < 4; ++r)
    t[ty + 8 * r][tx] = src[(size_t)(k0 + ty + 8 * r) * DIM + n0 + tx];
  __syncthreads();
  #pragma unroll
  for (int r = 0; r < 4; ++r)
    dst[(size_t)(n0 + ty + 8 * r) * DIM + k0 + tx] = f2b(t[tx][ty + 8 * r]);
}

// ---------- gather + cast x -> xp bf16 ----------
__global__ __launch_bounds__(256) void gather_cast(const float* __restrict__ x,
                                                   const int* __restrict__ perm,
                                                   u16* __restrict__ xpb) {
  const int i = blockIdx.x;
  const int src = perm[i];
  const int tid = threadIdx.x;
  float4 v = ((const float4*)(x + (size_t)src * DIM))[tid];
  ushort4 o;
  o.x = f2b(v.x); o.y = f2b(v.y); o.z = f2b(v.z); o.w = f2b(v.w);
  ((ushort4*)(xpb + (size_t)i * DIM))[tid] = o;
}

// ---------- QKV GEMM: BK=64, T2 swizzle; z==2 writes V^T via LDS transpose ----------
__global__ __launch_bounds__(256) void gemm_qkv(const u16* __restrict__ X,
                                                const u16* __restrict__ WTall,
                                                float qscale,
                                                u16* __restrict__ oq,
                                                u16* __restrict__ ok,
                                                u16* __restrict__ vT,
                                                const int* __restrict__ cntp) {
  const int z = blockIdx.z;                  // 0=q 1=k 2=v
  const int e = blockIdx.y >> 4;
  const int mt = blockIdx.y & 15;
  const int c0 = cntp[0];
  const int lo = e ? c0 : 0;
  const int hi = e ? N_TOK : c0;
  const int rb = mt * 128;
  if (rb >= hi || rb + 128 <= lo) return;
  const int cb = blockIdx.x * 128;
  const u16* W = WTall + ((size_t)(z * 2 + e) << 20);
  const float scl = (z == 0) ? qscale : 1.f;

  const int tid = threadIdx.x;
  const int w = tid >> 6, l = tid & 63, lg = l >> 4, ln = l & 15;
  const int wm = (w >> 1) * 64, wn = (w & 1) * 64;

  __shared__ __align__(16) char smem[65536];   // 2 bufs x (A 16K + B 16K)

  auto stage = [&](int it, int b_) {
    #pragma unroll
    for (int c = 0; c < 8; ++c) {
      const int j = tid + c * 256;             // 0..2047
      const int isB = j >> 10;
      const int cc = j & 1023;
      const int row = cc >> 3;
      const int colb = ((cc & 7) * 16) ^ ((row & 7) << 4);  // pre-swizzled source
      const char* base = isB ? (const char*)W + (size_t)(cb + row) * 2048
                             : (const char*)X + (size_t)(rb + row) * 2048;
      g2l16(base + it * 128 + colb, &smem[b_ * 32768 + isB * 16384 + cc * 16]);
    }
  };

  f32x4 acc[4][4];
  #pragma unroll
  for (int i = 0; i < 4; ++i)
    #pragma unroll
    for (int j = 0; j < 4; ++j) acc[i][j] = (f32x4){0.f, 0.f, 0.f, 0.f};

  const int aswz = (ln & 7) << 4;
  stage(0, 0);
  __syncthreads();
  for (int ii = 0; ii < 16; ++ii) {
    const int b_ = ii & 1;
    if (ii < 15) stage(ii + 1, b_ ^ 1);
    #pragma unroll
    for (int ks = 0; ks < 2; ++ks) {
      short8v a[4], bb[4];
      #pragma unroll
      for (int mi = 0; mi < 4; ++mi)
        a[mi] = *(const short8v*)&smem[b_ * 32768 + (wm + mi * 16 + ln) * 128 +
                                       ((ks * 64 + lg * 16) ^ aswz)];
      #pragma unroll
      for (int ni = 0; ni < 4; ++ni)
        bb[ni] = *(const short8v*)&smem[b_ * 32768 + 16384 + (wn + ni * 16 + ln) * 128 +
                                        ((ks * 64 + lg * 16) ^ aswz)];
      __builtin_amdgcn_s_setprio(1);
      #pragma unroll
      for (int mi = 0; mi < 4; ++mi)
        #pragma unroll
        for (int ni = 0; ni < 4; ++ni)
          acc[mi][ni] = MFMA(a[mi], bb[ni], acc[mi][ni], 0, 0, 0);
      __builtin_amdgcn_s_setprio(0);
    }
    __syncthreads();
  }

  if (z < 2) {
    u16* OUT = z ? ok : oq;
    #pragma unroll
    for (int mi = 0; mi < 4; ++mi) {
      #pragma unroll
      for (int r = 0; r < 4; ++r) {
        const int row = rb + wm + mi * 16 + lg * 4 + r;
        if (row >= lo && row < hi) {
          #pragma unroll
          for (int ni = 0; ni < 4; ++ni)
            OUT[(size_t)row * DIM + cb + wn + ni * 16 + ln] = f2b(acc[mi][ni][r] * scl);
        }
      }
    }
  } else {
    // V^T epilogue: transpose acc [token][dim] -> vT[dim][token] via LDS.
    // tb layout: [128 dims][264 B rows] (4B-bank pad -> conflict-free).
    #pragma unroll
    for (int mi = 0; mi < 4; ++mi)
      #pragma unroll
      for (int ni = 0; ni < 4; ++ni) {
        const int dim = wn + ni * 16 + ln;
        const int tok = wm + mi * 16 + lg * 4;
        u32 p01, p23;
        asm("v_cvt_pk_bf16_f32 %0, %1, %2" : "=v"(p01) : "v"(acc[mi][ni][0]), "v"(acc[mi][ni][1]));
        asm("v_cvt_pk_bf16_f32 %0, %1, %2" : "=v"(p23) : "v"(acc[mi][ni][2]), "v"(acc[mi][ni][3]));
        *(uint2*)&smem[dim * 264 + tok * 2] = make_uint2(p01, p23);
      }
    __syncthreads();
    #pragma unroll 4
    for (int rr = 0; rr < 32; ++rr) {
      const int dim = w * 32 + rr;
      const u32 val = *(const u32*)&smem[dim * 264 + l * 4];
      const int tok = rb + 2 * l;
      u16* dst = vT + (size_t)(cb + dim) * 2048 + tok;
      if (tok >= lo && tok + 2 <= hi) {
        *(u32*)dst = val;
      } else {
        if (tok >= lo && tok < hi) dst[0] = (u16)(val & 0xFFFFu);
        if (tok + 1 >= lo && tok + 1 < hi) dst[1] = (u16)(val >> 16);
      }
    }
  }
}

// ---------- out-proj GEMM: 128x64 tile, BK=64, split-K2, f32 partials ----------
__global__ __launch_bounds__(256) void gemm_out(const u16* __restrict__ X,
                                                const u16* __restrict__ WTall,
                                                float* __restrict__ o0,
                                                float* __restrict__ o1,
                                                const int* __restrict__ cntp) {
  const int z = blockIdx.z;                  // K-half
  const int e = blockIdx.y >> 4;
  const int mt = blockIdx.y & 15;
  const int c0 = cntp[0];
  const int lo = e ? c0 : 0;
  const int hi = e ? N_TOK : c0;
  const int rb = mt * 128;
  if (rb >= hi || rb + 128 <= lo) return;
  const int cb = blockIdx.x * 64;
  float* OUT = z ? o1 : o0;
  const u16* W = WTall + ((size_t)(6 + e) << 20);
  const int kstart = z * 8;

  const int tid = threadIdx.x;
  const int w = tid >> 6, l = tid & 63, lg = l >> 4, ln = l & 15;
  const int wm = w * 32;

  __shared__ __align__(16) char smem[49152];   // 2 bufs x (A 16K + B 8K)

  auto stage = [&](int it, int b_) {
    #pragma unroll
    for (int c = 0; c < 6; ++c) {
      const int j = tid + c * 256;             // 0..1535
      const int isB = j >= 1024;
      const int cc = isB ? (j - 1024) : j;
      const int row = cc >> 3;
      const int colb = ((cc & 7) * 16) ^ ((row & 7) << 4);
      const char* base = isB ? (const char*)W + (size_t)(cb + row) * 2048
                             : (const char*)X + (size_t)(rb + row) * 2048;
      g2l16(base + it * 128 + colb, &smem[b_ * 24576 + isB * 16384 + cc * 16]);
    }
  };

  f32x4 acc[2][4];
  #pragma unroll
  for (int i = 0; i < 2; ++i)
    #pragma unroll
    for (int j = 0; j < 4; ++j) acc[i][j] = (f32x4){0.f, 0.f, 0.f, 0.f};

  const int aswz = (ln & 7) << 4;
  stage(kstart, 0);
  __syncthreads();
  for (int ii = 0; ii < 8; ++ii) {
    const int b_ = ii & 1;
    if (ii < 7) stage(kstart + ii + 1, b_ ^ 1);
    #pragma unroll
    for (int ks = 0; ks < 2; ++ks) {
      short8v a[2], bb[4];
      #pragma unroll
      for (int mi = 0; mi < 2; ++mi)
        a[mi] = *(const short8v*)&smem[b_ * 24576 + (wm + mi * 16 + ln) * 128 +
                                       ((ks * 64 + lg * 16) ^ aswz)];
      #pragma unroll
      for (int ni = 0; ni < 4; ++ni)
        bb[ni] = *(const short8v*)&smem[b_ * 24576 + 16384 + (ni * 16 + ln) * 128 +
                                        ((ks * 64 + lg * 16) ^ aswz)];
      __builtin_amdgcn_s_setprio(1);
      #pragma unroll
      for (int mi = 0; mi < 2; ++mi)
        #pragma unroll
        for (int ni = 0; ni < 4; ++ni)
          acc[mi][ni] = MFMA(a[mi], bb[ni], acc[mi][ni], 0, 0, 0);
      __builtin_amdgcn_s_setprio(0);
    }
    __syncthreads();
  }

  #pragma unroll
  for (int mi = 0; mi < 2; ++mi) {
    #pragma unroll
    for (int r = 0; r < 4; ++r) {
      const int row = rb + wm + mi * 16 + lg * 4 + r;
      if (row >= lo && row < hi) {
        #pragma unroll
        for (int ni = 0; ni < 4; ++ni)
          OUT[(size_t)row * DIM + cb + ni * 16 + ln] = acc[mi][ni][r];
      }
    }
  }
}

// ---------- flash attention: barrier-free, wave-private K/V, depth-2 pipeline ----------
// grid: 512 blocks (32 qtiles x 16 heads, XCD-swizzled); block = 4 waves.
// Wave w = key-quarter kq: 64 q rows (2 B-frag sets) x 512 keys (16 iters of 32).
// Private 16KB LDS slice per wave: double-buffered (K 4K + V 4K) x 2.
// loads issued 2 iters ahead; ds_writes wait on loads aged a full iteration.
// No __syncthreads in main loop; 4-way split-K merge at the end.
__global__ __launch_bounds__(256, 2) void attn_fwd(const u16* __restrict__ qg,
                                                   const u16* __restrict__ kg,
                                                   const u16* __restrict__ vTg,
                                                   u16* __restrict__ og) {
  const int bid = blockIdx.x;
  const int wg = (bid & 7) * 64 + (bid >> 3);   // bijective XCD swizzle (512 = 8*64)
  const int qt = wg & 31, h = wg >> 5;
  const int tid = threadIdx.x, kq = tid >> 6, l = tid & 63;
  const int q31 = l & 31, hi = l >> 5;
  const int hi16 = hi * 16, hi4 = hi * 4;

  __shared__ __align__(16) char smem[67584];   // 4 waves x 16KB dbuf + 2KB merge
  const int base = kq * 16384;

  // per-lane staging source bases (inverse-swizzled so LDS writes are linear)
  const int lr3 = l >> 3, lc3 = l & 7;
  const char* baseK = (const char*)kg + (size_t)(kq * 512 + lr3) * 2048 + h * 128 +
                      ((lc3 << 4) ^ (lr3 << 4));
  const int cpr = lc3 ^ lr3;                  // swizzled col/16 for V
  const int dhalf = (cpr >> 2) & 1;
  const char* baseV = (const char*)vTg + (size_t)(h * 64 + lr3 + dhalf * 32) * 4096 +
                      kq * 1024 + ((cpr & 3) << 4);

  // Q fragments (B-operand), 2 sets of 32 q-cols
  const char* qb0 = (const char*)qg + (size_t)(qt * 64 + q31) * 2048 + h * 128;
  short8v qfA[4], qfB[4];
  #pragma unroll
  for (int t = 0; t < 4; ++t) {
    qfA[t] = *(const short8v*)(qb0 + t * 32 + hi16);
    qfB[t] = *(const short8v*)(qb0 + 65536 + t * 32 + hi16);
  }

  uint4 rk0, rk1, rk2, rk3, rv0, rv1, rv2, rv3;
  auto loadKV = [&](int it) {
    const char* pk = baseK + (size_t)it * 65536;   // 32 key-rows x 2048B
    rk0 = *(const uint4*)(pk);
    rk1 = *(const uint4*)(pk + 16384);
    rk2 = *(const uint4*)(pk + 32768);
    rk3 = *(const uint4*)(pk + 49152);
    const char* pv = baseV + it * 64;              // 32 keys x 2B
    rv0 = *(const uint4*)(pv);
    rv1 = *(const uint4*)(pv + 32768);
    rv2 = *(const uint4*)(pv + 65536);
    rv3 = *(const uint4*)(pv + 98304);
  };
  auto writeK = [&](int b_) {
    const int Kb = base + b_ * 8192;
    *(uint4*)&smem[Kb + 0 + l * 16] = rk0;
    *(uint4*)&smem[Kb + 1024 + l * 16] = rk1;
    *(uint4*)&smem[Kb + 2048 + l * 16] = rk2;
    *(uint4*)&smem[Kb + 3072 + l * 16] = rk3;
  };
  auto writeV = [&](int b_) {
    const int Vb = base + b_ * 8192 + 4096;
    *(uint4*)&smem[Vb + 0 + l * 16] = rv0;
    *(uint4*)&smem[Vb + 1024 + l * 16] = rv1;
    *(uint4*)&smem[Vb + 2048 + l * 16] = rv2;
    *(uint4*)&smem[Vb + 3072 + l * 16] = rv3;
  };

  float mA = -1e30f, lA = 0.f, mB = -1e30f, lB = 0.f;
  f32x16 accA0, accA1, accB0, accB1;
  #pragma unroll
  for (int r = 0; r < 16; ++r) { accA0[r] = 0.f; accA1[r] = 0.f; accB0[r] = 0.f; accB1[r] = 0.f; }

  struct PA { short8v p0, p1; };
  auto softmax = [&](f32x16& s_, float& m_s, float& l_s, f32x16& a0, f32x16& a1) -> PA {
    float t0 = fmaxf(fmaxf(s_[0], s_[1]), fmaxf(s_[2], s_[3]));
    float t1 = fmaxf(fmaxf(s_[4], s_[5]), fmaxf(s_[6], s_[7]));
    float t2 = fmaxf(fmaxf(s_[8], s_[9]), fmaxf(s_[10], s_[11]));
    float t3 = fmaxf(fmaxf(s_[12], s_[13]), fmaxf(s_[14], s_[15]));
    float tmax = fmaxf(fmaxf(t0, t1), fmaxf(t2, t3));
    tmax = fmaxf(tmax, __shfl_xor(tmax, 32, 64));
    if (!__all(tmax <= m_s + 11.0f)) {        // defer-max (T13)
      const float mn = fmaxf(m_s, tmax);
      const float al = __builtin_amdgcn_exp2f(m_s - mn);
      m_s = mn;
      l_s *= al;
      #pragma unroll
      for (int r = 0; r < 16; ++r) {
        const float ar = __shfl(al, (r & 3) + 8 * (r >> 2) + hi4, 64);
        a0[r] *= ar;
        a1[r] *= ar;
      }
    }
    float p[16];
    #pragma unroll
    for (int r = 0; r < 16; ++r) p[r] = __builtin_amdgcn_exp2f(s_[r] - m_s);
    float rs = ((p[0] + p[1]) + (p[2] + p[3])) + ((p[4] + p[5]) + (p[6] + p[7])) +
               (((p[8] + p[9]) + (p[10] + p[11])) + ((p[12] + p[13]) + (p[14] + p[15])));
    rs += __shfl_xor(rs, 32, 64);
    l_s += rs;
    u32 c0, c1, c2, c3, c4, c5, c6, c7;
    asm("v_cvt_pk_bf16_f32 %0, %1, %2" : "=v"(c0) : "v"(p[0]), "v"(p[1]));
    asm("v_cvt_pk_bf16_f32 %0, %1, %2" : "=v"(c1) : "v"(p[2]), "v"(p[3]));
    asm("v_cvt_pk_bf16_f32 %0, %1, %2" : "=v"(c2) : "v"(p[4]), "v"(p[5]));
    asm("v_cvt_pk_bf16_f32 %0, %1, %2" : "=v"(c3) : "v"(p[6]), "v"(p[7]));
    asm("v_cvt_pk_bf16_f32 %0, %1, %2" : "=v"(c4) : "v"(p[8]), "v"(p[9]));
    asm("v_cvt_pk_bf16_f32 %0, %1, %2" : "=v"(c5) : "v"(p[10]), "v"(p[11]));
    asm("v_cvt_pk_bf16_f32 %0, %1, %2" : "=v"(c6) : "v"(p[12]), "v"(p[13]));
    asm("v_cvt_pk_bf16_f32 %0, %1, %2" : "=v"(c7) : "v"(p[14]), "v"(p[15]));
    asm volatile("v_permlane32_swap_b32 %0, %1" : "+v"(c0), "+v"(c2));
    asm volatile("v_permlane32_swap_b32 %0, %1" : "+v"(c1), "+v"(c3));
    asm volatile("v_permlane32_swap_b32 %0, %1" : "+v"(c4), "+v"(c6));
    asm volatile("v_permlane32_swap_b32 %0, %1" : "+v"(c5), "+v"(c7));
    union { u32 u[4]; short8v s; } u0, u1;
    u0.u[0] = c0; u0.u[1] = c1; u0.u[2] = c2; u0.u[3] = c3;
    u1.u[0] = c4; u1.u[1] = c5; u1.u[2] = c6; u1.u[3] = c7;
    PA out;
    out.p0 = u0.s;
    out.p1 = u1.s;
    return out;
  };

  const int kswz = (q31 & 7) << 4;
  loadKV(0);
  writeK(0);
  writeV(0);
  loadKV(1);

  #pragma unroll 1
  for (int it = 0; it < 16; ++it) {
    const int cur = it & 1, nxt = cur ^ 1;
    const int Kb = base + cur * 8192, Vb = Kb + 4096;
    // K frags (lane = key row q31)
    short8v kf0 = *(const short8v*)&smem[Kb + q31 * 128 + ((0 + hi16) ^ kswz)];
    short8v kf1 = *(const short8v*)&smem[Kb + q31 * 128 + ((32 + hi16) ^ kswz)];
    short8v kf2 = *(const short8v*)&smem[Kb + q31 * 128 + ((64 + hi16) ^ kswz)];
    short8v kf3 = *(const short8v*)&smem[Kb + q31 * 128 + ((96 + hi16) ^ kswz)];
    f32x16 sA, sB;
    #pragma unroll
    for (int r = 0; r < 16; ++r) { sA[r] = 0.f; sB[r] = 0.f; }
    __builtin_amdgcn_s_setprio(1);
    sA = MFMA32(kf0, qfA[0], sA, 0, 0, 0);
    sB = MFMA32(kf0, qfB[0], sB, 0, 0, 0);
    sA = MFMA32(kf1, qfA[1], sA, 0, 0, 0);
    sB = MFMA32(kf1, qfB[1], sB, 0, 0, 0);
    sA = MFMA32(kf2, qfA[2], sA, 0, 0, 0);
    sB = MFMA32(kf2, qfB[2], sB, 0, 0, 0);
    sA = MFMA32(kf3, qfA[3], sA, 0, 0, 0);
    sB = MFMA32(kf3, qfB[3], sB, 0, 0, 0);
    __builtin_amdgcn_s_setprio(0);
    if (it < 15) writeK(nxt);                 // loads aged a full iter -> no stall

    PA pA = softmax(sA, mA, lA, accA0, accA1);
    PA pB = softmax(sB, mB, lB, accB0, accB1);

    // V frags: row = q31 (d), paired-d 128B rows
    short8v vf00 = *(const short8v*)&smem[Vb + q31 * 128 + ((0 + hi16) ^ kswz)];
    short8v vf01 = *(const short8v*)&smem[Vb + q31 * 128 + ((64 + hi16) ^ kswz)];
    short8v vf10 = *(const short8v*)&smem[Vb + q31 * 128 + ((32 + hi16) ^ kswz)];
    short8v vf11 = *(const short8v*)&smem[Vb + q31 * 128 + ((96 + hi16) ^ kswz)];
    __builtin_amdgcn_s_setprio(1);
    accA0 = MFMA32(pA.p0, vf00, accA0, 0, 0, 0);
    accA1 = MFMA32(pA.p0, vf01, accA1, 0, 0, 0);
    accB0 = MFMA32(pB.p0, vf00, accB0, 0, 0, 0);
    accB1 = MFMA32(pB.p0, vf01, accB1, 0, 0, 0);
    accA0 = MFMA32(pA.p1, vf10, accA0, 0, 0, 0);
    accA1 = MFMA32(pA.p1, vf11, accA1, 0, 0, 0);
    accB0 = MFMA32(pB.p1, vf10, accB0, 0, 0, 0);
    accB1 = MFMA32(pB.p1, vf11, accB1, 0, 0, 0);
    __builtin_amdgcn_s_setprio(0);
    if (it < 15) writeV(nxt);
    if (it < 14) loadKV(it + 2);
  }
  __syncthreads();

  // ---- 4-way split-K merge (staging LDS dead; reuse) ----
  float* mm = (float*)&smem[65536];           // m[set][kq][32], l at +256 floats
  if (l < 32) {
    mm[(0 * 4 + kq) * 32 + l] = mA;
    mm[(1 * 4 + kq) * 32 + l] = mB;
    mm[256 + (0 * 4 + kq) * 32 + l] = lA;
    mm[256 + (1 * 4 + kq) * 32 + l] = lB;
  }
  __syncthreads();
  float MA = mm[0 * 32 + q31], MB = mm[4 * 32 + q31];
  #pragma unroll
  for (int j = 1; j < 4; ++j) {
    MA = fmaxf(MA, mm[(0 * 4 + j) * 32 + q31]);
    MB = fmaxf(MB, mm[(1 * 4 + j) * 32 + q31]);
  }
  float LA = 0.f, LB = 0.f;
  #pragma unroll
  for (int j = 0; j < 4; ++j) {
    LA += mm[256 + (0 * 4 + j) * 32 + q31] * __builtin_amdgcn_exp2f(mm[(0 * 4 + j) * 32 + q31] - MA);
    LB += mm[256 + (1 * 4 + j) * 32 + q31] * __builtin_amdgcn_exp2f(mm[(1 * 4 + j) * 32 + q31] - MB);
  }
  const float aA = __builtin_amdgcn_exp2f(mA - MA), liA = 1.f / LA;
  const float aB = __builtin_amdgcn_exp2f(mB - MB), liB = 1.f / LB;

  float* obuf = (float*)&smem[0];             // [64 q][64 d] f32
  #pragma unroll
  for (int round = 3; round >= 0; --round) {
    if (kq == round) {
      #pragma unroll
      for (int r = 0; r < 16; ++r) {
        const int qr = (r & 3) + 8 * (r >> 2) + hi4;
        const float arA = __shfl(aA, qr, 64);
        const float arB = __shfl(aB, qr, 64);
        float* pa0 = &obuf[qr * 64 + q31];
        float* pa1 = &obuf[qr * 64 + 32 + q31];
        float* pb0 = &obuf[(32 + qr) * 64 + q31];
        float* pb1 = &obuf[(32 + qr) * 64 + 32 + q31];
        if (round == 3) {
          *pa0 = accA0[r] * arA; *pa1 = accA1[r] * arA;
          *pb0 = accB0[r] * arB; *pb1 = accB1[r] * arB;
        } else if (round > 0) {
          *pa0 += accA0[r] * arA; *pa1 += accA1[r] * arA;
          *pb0 += accB0[r] * arB; *pb1 += accB1[r] * arB;
        } else {
          const float lrA = __shfl(liA, qr, 64);
          const float lrB = __shfl(liB, qr, 64);
          const int rowA = qt * 64 + qr, rowB = qt * 64 + 32 + qr;
          og[(size_t)rowA * DIM + h * HD + q31] = f2b((accA0[r] * arA + *pa0) * lrA);
          og[(size_t)rowA * DIM + h * HD + 32 + q31] = f2b((accA1[r] * arA + *pa1) * lrA);
          og[(size_t)rowB * DIM + h * HD + q31] = f2b((accB0[r] * arB + *pb0) * lrB);
          og[(size_t)rowB * DIM + h * HD + 32 + q31] = f2b((accB1[r] * arB + *pb1) * lrB);
        }
      }
    }
    __syncthreads();
  }
}

// ---------- LayerNorm + per-modality affine + scatter (sums split-K partials) ----------
__global__ __launch_bounds__(256) void ln_scatter(const float* __restrict__ oa,
                                                  const float* __restrict__ ob,
                                                  const float* __restrict__ lnw,
                                                  const float* __restrict__ lnb,
                                                  const int* __restrict__ perm,
                                                  const int* __restrict__ cntp,
                                                  float* __restrict__ out) {
  const int i = blockIdx.x;
  const int tid = threadIdx.x, w = tid >> 6, l = tid & 63;
  const int mod = (i < cntp[0]) ? 0 : 1;
  float4 va = ((const float4*)(oa + (size_t)i * DIM))[tid];
  float4 vb = ((const float4*)(ob + (size_t)i * DIM))[tid];
  float4 v;
  v.x = va.x + vb.x; v.y = va.y + vb.y; v.z = va.z + vb.z; v.w = va.w + vb.w;
  float s = v.x + v.y + v.z + v.w;
  float ss = v.x * v.x + v.y * v.y + v.z * v.z + v.w * v.w;
  #pragma unroll
  for (int off = 1; off < 64; off <<= 1) {
    s += __shfl_xor(s, off, 64);
    ss += __shfl_xor(ss, off, 64);
  }
  __shared__ float rs4[4], rss4[4];
  if (l == 0) { rs4[w] = s; rss4[w] = ss; }
  __syncthreads();
  const float st = rs4[0] + rs4[1] + rs4[2] + rs4[3];
  const float sst = rss4[0] + rss4[1] + rss4[2] + rss4[3];
  const float mu = st * (1.f / DIM);
  const float var = sst * (1.f / DIM) - mu * mu;
  const float rstd = rsqrtf(var + 1e-5f);
  const int drow = perm[i];
  float4 g = ((const float4*)(lnw + (size_t)mod * DIM))[tid];
  float4 b = ((const float4*)(lnb + (size_t)mod * DIM))[tid];
  float4 rr;
  rr.x = (v.x - mu) * rstd * g.x + b.x;
  rr.y = (v.y - mu) * rstd * g.y + b.y;
  rr.z = (v.z - mu) * rstd * g.z + b.z;
  rr.w = (v.w - mu) * rstd * g.w + b.w;
  ((float4*)(out + (size_t)drow * DIM))[tid] = rr;
}

// ---------- launch ----------
extern "C" void kernel_launch(void* const* d_in, const int* in_sizes, int n_in,
                              void* d_out, int out_size, void* d_ws, size_t ws_size,
                              hipStream_t stream) {
  const float* x = (const float*)d_in[0];
  const void* masks = d_in[1];
  const float* wq = (const float*)d_in[3];
  const float* wk = (const float*)d_in[4];
  const float* wv = (const float*)d_in[5];
  const float* wo = (const float*)d_in[6];
  const float* lnw = (const float*)d_in[7];
  const float* lnb = (const float*)d_in[8];

  char* ws = (char*)d_ws;
  int* perm = (int*)(ws + OFF_PERM);
  int* cnt = (int*)(ws + OFF_CNT);
  u16* xpb = (u16*)(ws + OFF_XPB);
  u16* wT = (u16*)(ws + OFF_WT);
  u16* q = (u16*)(ws + OFF_Q);
  u16* k = (u16*)(ws + OFF_K);
  u16* vT = (u16*)(ws + OFF_VT);
  u16* at = (u16*)(ws + OFF_AT);
  float* o = (float*)(ws + OFF_O);
  float* o2 = (float*)(ws + OFF_O2);
  float* out = (float*)d_out;

  wcast_prep<<<dim3(32, 32, 9), dim3(32, 8), 0, stream>>>(wq, wk, wv, wo, wT, masks, perm, cnt);
  gather_cast<<<N_TOK, 256, 0, stream>>>(x, perm, xpb);
  gemm_qkv<<<dim3(8, 32, 3), 256, 0, stream>>>(xpb, wT, QSCALE, q, k, vT, cnt);
  attn_fwd<<<512, 256, 0, stream>>>(q, k, vT, at);
  gemm_out<<<dim3(16, 32, 2), 256, 0, stream>>>(at, wT, o, o2, cnt);
  ln_scatter<<<N_TOK, 256, 0, stream>>>(o, o2, lnw, lnb, perm, cnt, out);
}